// Round 16
// baseline (1309.985 us; speedup 1.0000x reference)
//
#include <hip/hip_runtime.h>
#include <hip/hip_bf16.h>
#include <math.h>

// xLSTM block stack: 8 sequential blocks, then post-LN + projection.
// Round 15: chg -> measured-best 4-row/1472-block geometry + __expf.
//           Rest = R14 (scan, GEMMs, mlstm, lnres, proj unchanged).
//
#define SB   64            // batch
#define SS   46            // seq
#define SE   1024          // embed
#define SI   2048          // inner
#define ROWS (SB*SS)       // 2944
#define NHH  4             // mLSTM heads
#define DHH  512           // head dim
#define NHQ_ 512           // headwise 4x4 heads
#define OUTD 512
#define KSPLIT 4

typedef __attribute__((ext_vector_type(8))) short bf16x8;
typedef __attribute__((ext_vector_type(4))) short bf16x4;
typedef __attribute__((ext_vector_type(4))) float f32x4;

__device__ __forceinline__ void gload_lds16(const void* g, void* lds) {
  __builtin_amdgcn_global_load_lds(
      (const __attribute__((address_space(1))) unsigned int*)g,
      (__attribute__((address_space(3))) unsigned int*)lds, 16, 0, 0);
}

__device__ __forceinline__ float bf2f(short s) {
  union { unsigned int u; float f; } x;
  x.u = ((unsigned int)(unsigned short)s) << 16;
  return x.f;
}

__device__ __forceinline__ short f2bf_rne(float f) {
  union { float f; unsigned int u; } cv; cv.f = f;
  unsigned int lsb = (cv.u >> 16) & 1;
  cv.u += 0x7fff + lsb;
  return (short)(cv.u >> 16);
}

__device__ __forceinline__ float fexp(float x) { return __expf(x); }

// ---------------------------------------------------------------------------
// Residual-add (npart bf16 split-K partials) + LayerNorm -> bf16; xbuf updated.
__global__ __launch_bounds__(256) void lnres_bf16_kernel(
    float* __restrict__ xbuf, const __hip_bfloat16* __restrict__ parts, int npart,
    const float* __restrict__ w, __hip_bfloat16* __restrict__ out) {
  const int row = blockIdx.x;
  const int t = threadIdx.x;
  const int i0 = t * 4;
  float vals[4];
  {
    const float4 xv = *(const float4*)(xbuf + (size_t)row*SE + i0);
    vals[0] = xv.x; vals[1] = xv.y; vals[2] = xv.z; vals[3] = xv.w;
  }
  for (int p = 0; p < npart; ++p) {
    const bf16x4 pv = *(const bf16x4*)((const short*)parts +
        (size_t)p*ROWS*SE + (size_t)row*SE + i0);
#pragma unroll
    for (int j = 0; j < 4; ++j) vals[j] += bf2f(pv[j]);
  }
  float s1 = vals[0]+vals[1]+vals[2]+vals[3];
  float s2 = vals[0]*vals[0]+vals[1]*vals[1]+vals[2]*vals[2]+vals[3]*vals[3];
  if (npart) {
    float4 st = {vals[0], vals[1], vals[2], vals[3]};
    *(float4*)(xbuf + (size_t)row*SE + i0) = st;
  }
  __shared__ float r1[4], r2[4];
  for (int off = 32; off; off >>= 1) { s1 += __shfl_down(s1, off); s2 += __shfl_down(s2, off); }
  if ((t & 63) == 0) { r1[t >> 6] = s1; r2[t >> 6] = s2; }
  __syncthreads();
  s1 = r1[0]+r1[1]+r1[2]+r1[3];
  s2 = r2[0]+r2[1]+r2[2]+r2[3];
  const float mu = s1 * (1.f/SE);
  const float var = s2 * (1.f/SE) - mu*mu;
  const float rs = rsqrtf(var + 1e-5f);
  const float4 w4 = *(const float4*)(w + i0);
  const float wv[4] = {w4.x, w4.y, w4.z, w4.w};
  bf16x4 o;
#pragma unroll
  for (int j = 0; j < 4; ++j) o[j] = f2bf_rne((vals[j]-mu)*rs*wv[j]);
  *(bf16x4*)((short*)out + (size_t)row*SE + i0) = o;
}

// ---------------------------------------------------------------------------
// Transpose + convert (all 8 layers): W [z][K][N] fp32 -> Wt [z][N][K] bf16.
__global__ __launch_bounds__(256) void transpose_bf16_kernel(
    const float* __restrict__ W, __hip_bfloat16* __restrict__ Wt, int K, int N) {
  __shared__ float tile[32][33];
  const int z = blockIdx.z;
  const float* Wz = W + (size_t)z*K*N;
  __hip_bfloat16* Wtz = Wt + (size_t)z*K*N;
  const int k0 = blockIdx.y * 32, n0 = blockIdx.x * 32;
  const int tr = threadIdx.x >> 5;
  const int tc = threadIdx.x & 31;
#pragma unroll
  for (int i = 0; i < 4; ++i)
    tile[tr + i*8][tc] = Wz[(size_t)(k0 + tr + i*8)*N + n0 + tc];
  __syncthreads();
#pragma unroll
  for (int i = 0; i < 4; ++i)
    Wtz[(size_t)(n0 + tr + i*8)*K + k0 + tc] = __float2bfloat16(tile[tc][tr + i*8]);
}

// ---------------------------------------------------------------------------
// bf16 MFMA GEMM: C[M,N] = A[M,K_z] * Bt[N,K_z]^T over this z's K-slice.
// 128x128 tile, BK=32, 2-phase pipelined K-loop (counted vmcnt, raw barriers).
// XCD-aware bijective block swizzle (requires gx*gy % 8 == 0).
__global__ __launch_bounds__(256) void gemm_mfma(
    const __hip_bfloat16* __restrict__ A, int lda,
    const __hip_bfloat16* __restrict__ Bt, int ldb,
    __hip_bfloat16* __restrict__ Cv, int ldc, int K, size_t cstride) {
  __shared__ short As[2][128*32];
  __shared__ short Bs[2][128*32];
  const int t = threadIdx.x;
  const int lane = t & 63;
  const int w = t >> 6;
  const int wr = w >> 1, wc = w & 1;
  const int l15 = lane & 15, lg = lane >> 4;

  const int nxy = gridDim.x * gridDim.y;
  int flat = blockIdx.y * gridDim.x + blockIdx.x;
  const int cpx = nxy >> 3;
  flat = (flat & 7) * cpx + (flat >> 3);
  const int bx = flat % gridDim.x;
  const int by = flat / gridDim.x;

  const int row0 = by * 128, col0 = bx * 128;
  const int Kper = K / gridDim.z;
  const int kbeg = blockIdx.z * Kper, kend = kbeg + Kper;
  f32x4 acc[4][4];
#pragma unroll
  for (int m = 0; m < 4; ++m)
#pragma unroll
    for (int n = 0; n < 4; ++n) acc[m][n] = (f32x4){0.f,0.f,0.f,0.f};

  const int L0 = t*16;
  const int L1 = 4096 + t*16;
  const int r0s = L0 >> 6, k0s = (L0 & 63) >> 1;
  const int r1s = L1 >> 6, k1s = (L1 & 63) >> 1;

#define STAGE(buf, kk0)                                                        \
  do {                                                                         \
    gload_lds16(A  + (size_t)(row0 + r0s)*lda + (kk0) + k0s, (char*)As[buf] + L0); \
    gload_lds16(A  + (size_t)(row0 + r1s)*lda + (kk0) + k1s, (char*)As[buf] + L1); \
    gload_lds16(Bt + (size_t)(col0 + r0s)*ldb + (kk0) + k0s, (char*)Bs[buf] + L0); \
    gload_lds16(Bt + (size_t)(col0 + r1s)*ldb + (kk0) + k1s, (char*)Bs[buf] + L1); \
  } while (0)

  int cur = 0;
  STAGE(0, kbeg);
  for (int k0 = kbeg; k0 < kend; k0 += 32) {
    const bool haveNext = (k0 + 32 < kend);
    if (haveNext) {
      STAGE(cur ^ 1, k0 + 32);
      asm volatile("s_waitcnt vmcnt(4)" ::: "memory");
    } else {
      asm volatile("s_waitcnt vmcnt(0)" ::: "memory");
    }
    __builtin_amdgcn_sched_barrier(0);
    __builtin_amdgcn_s_barrier();
    bf16x8 af[4], bfr[4];
#pragma unroll
    for (int m = 0; m < 4; ++m)
      af[m] = *(const bf16x8*)&As[cur][(wr*64 + m*16 + l15)*32 + lg*8];
#pragma unroll
    for (int n = 0; n < 4; ++n)
      bfr[n] = *(const bf16x8*)&Bs[cur][(wc*64 + n*16 + l15)*32 + lg*8];
#pragma unroll
    for (int m = 0; m < 4; ++m)
#pragma unroll
      for (int n = 0; n < 4; ++n)
        acc[m][n] = __builtin_amdgcn_mfma_f32_16x16x32_bf16(af[m], bfr[n], acc[m][n], 0, 0, 0);
    asm volatile("s_waitcnt lgkmcnt(0)" ::: "memory");
    __builtin_amdgcn_sched_barrier(0);
    __builtin_amdgcn_s_barrier();
    cur ^= 1;
  }
#undef STAGE

  __hip_bfloat16* Cz = Cv + blockIdx.z * cstride;
#pragma unroll
  for (int m = 0; m < 4; ++m) {
#pragma unroll
    for (int n = 0; n < 4; ++n) {
      const int cc = col0 + wc*64 + n*16 + l15;
#pragma unroll
      for (int j = 0; j < 4; ++j) {
        const int rr = row0 + wr*64 + m*16 + lg*4 + j;
        Cz[(size_t)rr*ldc + cc] = __float2bfloat16(acc[m][n][j]);
      }
    }
  }
}

// ---------------------------------------------------------------------------
// Fused v5 (4 rows x 1024 channels per block; thread owns 4-channel group):
// causal conv(K=4)+SiLU -> xact bf16; headwise 4x4 q/k/v (thread-local) -> bf16;
// gate partials -> part[row][chunk*8+g], chunk in {0,1}.
__global__ __launch_bounds__(256) void conv_head_gate_kernel(
    const __hip_bfloat16* __restrict__ up, const float* __restrict__ cw,
    const float* __restrict__ cb,
    const float* __restrict__ wq, const float* __restrict__ wk,
    const float* __restrict__ wv,
    const float* __restrict__ igw, const float* __restrict__ fgw,
    __hip_bfloat16* __restrict__ xact,
    __hip_bfloat16* __restrict__ qb, __hip_bfloat16* __restrict__ kb,
    __hip_bfloat16* __restrict__ vb, float* __restrict__ part) {
  const int rblk  = blockIdx.x >> 1;       // 0..735 (4 rows each)
  const int chunk = blockIdx.x & 1;        // 0..1 (1024 channels each)
  const int r0 = rblk * 4;
  const int t = threadIdx.x;
  const int c4 = chunk*1024 + t*4;         // first of this thread's 4 channels
  const int lane = t & 63, wv_ = t >> 6;

  float wtap[4][4], bias[4];
#pragma unroll
  for (int j = 0; j < 4; ++j) {
    const float4 w4 = *(const float4*)(cw + (size_t)(c4 + j)*4);
    wtap[j][0] = w4.x; wtap[j][1] = w4.y; wtap[j][2] = w4.z; wtap[j][3] = w4.w;
  }
  {
    const float4 b4 = *(const float4*)(cb + c4);
    bias[0] = b4.x; bias[1] = b4.y; bias[2] = b4.z; bias[3] = b4.w;
  }
  const size_t hqo = (size_t)(c4 >> 2) * 16;
  float wqm[4][4], wkm[4][4], wvm[4][4];
#pragma unroll
  for (int o = 0; o < 4; ++o) {
    const float4 a = *(const float4*)(wq + hqo + o*4);
    const float4 b = *(const float4*)(wk + hqo + o*4);
    const float4 c = *(const float4*)(wv + hqo + o*4);
    wqm[o][0]=a.x; wqm[o][1]=a.y; wqm[o][2]=a.z; wqm[o][3]=a.w;
    wkm[o][0]=b.x; wkm[o][1]=b.y; wkm[o][2]=b.z; wkm[o][3]=b.w;
    wvm[o][0]=c.x; wvm[o][1]=c.y; wvm[o][2]=c.z; wvm[o][3]=c.w;
  }

  // input rows r0-3 .. r0+3 (7 rows) as short4
  bf16x4 u[7];
#pragma unroll
  for (int i = 0; i < 7; ++i) {
    const int gr = r0 - 3 + i;
    u[i] = (gr >= 0) ? *(const bf16x4*)((const short*)up + (size_t)gr*(2*SI) + c4)
                     : (bf16x4){0,0,0,0};
  }

  __shared__ float red[4][4][8];   // [row][wave][gate]

  const int h = c4 >> 9, dd = c4 & 511;
#pragma unroll
  for (int rr = 0; rr < 4; ++rr) {
    const int row = r0 + rr;
    const int b = row / SS, s = row - (row / SS)*SS;
    float xa[4], xin[4];
#pragma unroll
    for (int j = 0; j < 4; ++j) {
      float acc = bias[j];
#pragma unroll
      for (int tap = 0; tap < 4; ++tap)
        if (s - 3 + tap >= 0) acc += bf2f(u[rr + tap][j]) * wtap[j][tap];
      xa[j] = acc / (1.f + fexp(-acc));
      xin[j] = bf2f(u[rr + 3][j]);
    }
    {
      bf16x4 xo;
#pragma unroll
      for (int j = 0; j < 4; ++j) xo[j] = f2bf_rne(xa[j]);
      *(bf16x4*)((short*)xact + (size_t)row*SI + c4) = xo;
    }
    float q[4], k[4], v[4];
#pragma unroll
    for (int o = 0; o < 4; ++o) {
      float aq = 0.f, ak = 0.f, av = 0.f;
#pragma unroll
      for (int d = 0; d < 4; ++d) {
        aq += xa[d] * wqm[o][d];
        ak += xa[d] * wkm[o][d];
        av += xin[d] * wvm[o][d];
      }
      q[o] = aq; k[o] = ak; v[o] = av;
    }
    const size_t dst = (((size_t)b*NHH + h)*SS + s)*DHH + dd;
    {
      bf16x4 qo, ko, vo;
#pragma unroll
      for (int j = 0; j < 4; ++j) {
        qo[j] = f2bf_rne(q[j]); ko[j] = f2bf_rne(k[j]); vo[j] = f2bf_rne(v[j]);
      }
      *(bf16x4*)((short*)qb + dst) = qo;
      *(bf16x4*)((short*)kb + dst) = ko;
      *(bf16x4*)((short*)vb + dst) = vo;
    }
    float a8[8] = {0,0,0,0,0,0,0,0};
#pragma unroll
    for (int j = 0; j < 4; ++j) {
      const float4 wiq = *(const float4*)(igw + (size_t)(c4+j)*4);
      const float4 wik = *(const float4*)(igw + (size_t)(2048+c4+j)*4);
      const float4 wiv = *(const float4*)(igw + (size_t)(4096+c4+j)*4);
      const float4 wfq = *(const float4*)(fgw + (size_t)(c4+j)*4);
      const float4 wfk = *(const float4*)(fgw + (size_t)(2048+c4+j)*4);
      const float4 wfv = *(const float4*)(fgw + (size_t)(4096+c4+j)*4);
      a8[0] += q[j]*wiq.x + k[j]*wik.x + v[j]*wiv.x;
      a8[1] += q[j]*wiq.y + k[j]*wik.y + v[j]*wiv.y;
      a8[2] += q[j]*wiq.z + k[j]*wik.z + v[j]*wiv.z;
      a8[3] += q[j]*wiq.w + k[j]*wik.w + v[j]*wiv.w;
      a8[4] += q[j]*wfq.x + k[j]*wfk.x + v[j]*wfv.x;
      a8[5] += q[j]*wfq.y + k[j]*wfk.y + v[j]*wfv.y;
      a8[6] += q[j]*wfq.z + k[j]*wfk.z + v[j]*wfv.z;
      a8[7] += q[j]*wfq.w + k[j]*wfk.w + v[j]*wfv.w;
    }
    for (int off = 32; off; off >>= 1)
#pragma unroll
      for (int g = 0; g < 8; ++g) a8[g] += __shfl_down(a8[g], off);
    if (lane == 0)
#pragma unroll
      for (int g = 0; g < 8; ++g) red[rr][wv_][g] = a8[g];
  }
  __syncthreads();
  if (t < 32) {
    const int rr = t >> 3, g = t & 7;
    part[(size_t)(r0 + rr)*16 + chunk*8 + g] =
        red[rr][0][g] + red[rr][1][g] + red[rr][2][g] + red[rr][3][g];
  }
}

// ---------------------------------------------------------------------------
// mLSTM per (b,head), 8 waves (512 thr): gate reduce + MFMA QK^T + parallel
// log-sigmoid scan (Kogge-Stone in wave 0) + VALU PV + fused multi-head
// norm/skip/gate epilogue -> habf bf16 [b*s][2048].
__global__ __launch_bounds__(512) void mlstm_mfma_kernel(
    const __hip_bfloat16* __restrict__ qb, const __hip_bfloat16* __restrict__ kb,
    const __hip_bfloat16* __restrict__ vb,
    const float* __restrict__ part,
    const float* __restrict__ igb, const float* __restrict__ fgb,
    const __hip_bfloat16* __restrict__ xact, const __hip_bfloat16* __restrict__ up,
    const float* __restrict__ skip, const float* __restrict__ mhn,
    __hip_bfloat16* __restrict__ habf) {
  const int bh = blockIdx.x;                 // b*4 + h
  const int b = bh >> 2, h = bh & 3;
  const int t = threadIdx.x;
  const int lane = t & 63, wid = t >> 6;     // wid 0..7
  const int l15 = lane & 15, lg = lane >> 4;

  __shared__ short QKs[2][48*264];
  __shared__ float Cs[46][48];
  __shared__ float cum[46], mmv[46], ips[46], fps[46], inv[46];
  short* Vs = &QKs[0][0];                    // alias: V [46][520] bf16

  if (t < SS) {
    const float* pr = part + (size_t)(b*SS + t)*16;
    float si = igb[h], sf = fgb[h];
#pragma unroll
    for (int ch = 0; ch < 2; ++ch) { si += pr[ch*8 + h]; sf += pr[ch*8 + 4 + h]; }
    ips[t] = si; fps[t] = sf;
  }

  int prs[2]; int np = 0;
  for (int p = wid; p < 9; p += 8) prs[np++] = p;
  f32x4 acc[2];
#pragma unroll
  for (int i = 0; i < 2; ++i) acc[i] = (f32x4){0.f,0.f,0.f,0.f};

  for (int ph = 0; ph < 2; ++ph) {
    __syncthreads();
    for (int i = t; i < 48*32; i += 512) {
      const int row = i >> 5, oc = i & 31;
      bf16x8 vq = {0,0,0,0,0,0,0,0}, vk = {0,0,0,0,0,0,0,0};
      if (row < SS) {
        const size_t src = ((size_t)bh*SS + row)*DHH + ph*256 + oc*8;
        vq = *(const bf16x8*)(qb + src);
        vk = *(const bf16x8*)(kb + src);
      }
      *(bf16x8*)&QKs[0][row*264 + oc*8] = vq;
      *(bf16x8*)&QKs[1][row*264 + oc*8] = vk;
    }
    __syncthreads();
#pragma unroll
    for (int kc = 0; kc < 8; ++kc) {
      for (int i = 0; i < np; ++i) {
        const int mt = prs[i] / 3, nt = prs[i] - 3*(prs[i]/3);
        const bf16x8 a = *(const bf16x8*)&QKs[0][(mt*16 + l15)*264 + kc*32 + lg*8];
        const bf16x8 bb = *(const bf16x8*)&QKs[1][(nt*16 + l15)*264 + kc*32 + lg*8];
        acc[i] = __builtin_amdgcn_mfma_f32_16x16x32_bf16(a, bb, acc[i], 0, 0, 0);
      }
    }
  }
  __syncthreads();
  // parallel log-sigmoid cumsum + running-max scan (wave 0, Kogge-Stone)
  if (wid == 0) {
    const int s = lane;
    float lf = 0.f;
    if (s < SS) {
      const float xv = fps[s];
      lf = fminf(xv, 0.f) - log1pf(expf(-fabsf(xv)));
    }
#pragma unroll
    for (int off = 1; off < 64; off <<= 1) {
      const float o = __shfl_up(lf, off);
      if (lane >= off) lf += o;
    }
    float e = (s < SS) ? (ips[s] - lf) : -INFINITY;
#pragma unroll
    for (int off = 1; off < 64; off <<= 1) {
      const float o = __shfl_up(e, off);
      if (lane >= off) e = fmaxf(e, o);
    }
    if (s < SS) { cum[s] = lf; mmv[s] = lf + e; }
  }
  for (int i = t; i < SS*64; i += 512) {
    const int row = i >> 6, oc = i & 63;
    *(bf16x8*)&Vs[row*520 + oc*8] =
        *(const bf16x8*)(vb + ((size_t)bh*SS + row)*DHH + oc*8);
  }
  __syncthreads();
  const float rsq = 0.04419417382415922f;
  for (int i = 0; i < np; ++i) {
    const int mt = prs[i] / 3, nt = prs[i] - 3*(prs[i]/3);
    const int s = nt*16 + l15;
    if (s < SS) {
#pragma unroll
      for (int j = 0; j < 4; ++j) {
        const int tt = mt*16 + lg*4 + j;
        if (tt < SS) {
          float wgt = 0.f;
          if (s <= tt) wgt = rsq * fexp(cum[tt] - cum[s] + ips[s] - mmv[tt]);
          Cs[tt][s] = acc[i][j] * wgt;
        }
      }
    }
  }
  __syncthreads();
  if (t < SS) {
    float ssum = 0.f;
    for (int s = 0; s <= t; ++s) ssum += Cs[t][s];
    inv[t] = 1.f / (fmaxf(fabsf(ssum), fexp(-mmv[t])) + 1e-6f);
  }
  __syncthreads();
  const int c0 = h*DHH + lane*8;
  for (int it = 0; it < 6; ++it) {
    const int tt = wid + it*8;
    if (tt >= SS) break;
    float a[8];
#pragma unroll
    for (int j = 0; j < 8; ++j) a[j] = 0.f;
    for (int s = 0; s <= tt; ++s) {
      const float c = Cs[tt][s];
      const bf16x8 v8 = *(const bf16x8*)&Vs[s*520 + lane*8];
#pragma unroll
      for (int j = 0; j < 8; ++j) a[j] += c * bf2f(v8[j]);
    }
    const float sc = inv[tt];
    float s1 = 0.f, s2 = 0.f;
#pragma unroll
    for (int j = 0; j < 8; ++j) { a[j] *= sc; s1 += a[j]; s2 += a[j]*a[j]; }
#pragma unroll
    for (int off = 1; off < 64; off <<= 1) {
      s1 += __shfl_xor(s1, off); s2 += __shfl_xor(s2, off);
    }
    const float mu = s1 * (1.f/512.f);
    const float var = s2 * (1.f/512.f) - mu*mu;
    const float rs = rsqrtf(var + 1e-5f);
    const int row = b*SS + tt;
    const bf16x8 xa8 = *(const bf16x8*)((const short*)xact + (size_t)row*SI + c0);
    const bf16x8 z8 = *(const bf16x8*)((const short*)up + (size_t)row*(2*SI) + SI + c0);
    const float4 mh0 = *(const float4*)(mhn + c0);
    const float4 mh1 = *(const float4*)(mhn + c0 + 4);
    const float4 sk0 = *(const float4*)(skip + c0);
    const float4 sk1 = *(const float4*)(skip + c0 + 4);
    const float mhv[8] = {mh0.x,mh0.y,mh0.z,mh0.w,mh1.x,mh1.y,mh1.z,mh1.w};
    const float skv[8] = {sk0.x,sk0.y,sk0.z,sk0.w,sk1.x,sk1.y,sk1.z,sk1.w};
    bf16x8 o8;
#pragma unroll
    for (int j = 0; j < 8; ++j) {
      const float hv = (a[j]-mu)*rs*mhv[j] + skv[j]*bf2f(xa8[j]);
      const float zv = bf2f(z8[j]);
      o8[j] = f2bf_rne(hv * (zv / (1.f + fexp(-zv))));
    }
    *(bf16x8*)((short*)habf + (size_t)row*SI + c0) = o8;
  }
}

// ---------------------------------------------------------------------------
// Fused post-LN (residual + bf16 split-K partials) + projection.
__global__ __launch_bounds__(256) void proj_fused_kernel(
    const float* __restrict__ xbuf, const __hip_bfloat16* __restrict__ parts,
    const float* __restrict__ w, const float* __restrict__ pw,
    const float* __restrict__ pb, float* __restrict__ out) {
  const int b = blockIdx.x >> 3;
  const int och = blockIdx.x & 7;
  const int row = b*SS + SS - 1;
  const int t = threadIdx.x;
  const int wv_ = t >> 6, lane = t & 63;
  const int i0 = t * 4;
  float vals[4];
  {
    const float4 xv = *(const float4*)(xbuf + (size_t)row*SE + i0);
    vals[0] = xv.x; vals[1] = xv.y; vals[2] = xv.z; vals[3] = xv.w;
  }
#pragma unroll
  for (int p = 0; p < KSPLIT; ++p) {
    const bf16x4 pv = *(const bf16x4*)((const short*)parts +
        (size_t)p*ROWS*SE + (size_t)row*SE + i0);
#pragma unroll
    for (int j = 0; j < 4; ++j) vals[j] += bf2f(pv[j]);
  }
  float s1 = vals[0]+vals[1]+vals[2]+vals[3];
  float s2 = vals[0]*vals[0]+vals[1]*vals[1]+vals[2]*vals[2]+vals[3]*vals[3];
  __shared__ float r1[4], r2[4];
  __shared__ float xs[SE];
  __shared__ float red[4][64];
  for (int off = 32; off; off >>= 1) { s1 += __shfl_down(s1, off); s2 += __shfl_down(s2, off); }
  if (lane == 0) { r1[wv_] = s1; r2[wv_] = s2; }
  __syncthreads();
  s1 = r1[0]+r1[1]+r1[2]+r1[3];
  s2 = r2[0]+r2[1]+r2[2]+r2[3];
  const float mu = s1 * (1.f/SE);
  const float var = s2 * (1.f/SE) - mu*mu;
  const float rs = rsqrtf(var + 1e-5f);
  {
    const float4 w4 = *(const float4*)(w + i0);
    const float wv4[4] = {w4.x, w4.y, w4.z, w4.w};
#pragma unroll
    for (int j = 0; j < 4; ++j) xs[i0 + j] = (vals[j]-mu)*rs*wv4[j];
  }
  __syncthreads();
  const int o = och*64 + lane;
  float acc = 0.f;
  const int kbeg = wv_*256;
#pragma unroll 8
  for (int k = kbeg; k < kbeg + 256; ++k)
    acc += xs[k] * pw[(size_t)k*OUTD + o];
  red[wv_][lane] = acc;
  __syncthreads();
  if (t < 64)
    out[(size_t)b*OUTD + och*64 + t] =
        red[0][t] + red[1][t] + red[2][t] + red[3][t] + pb[och*64 + t];
}

// ---------------------------------------------------------------------------
extern "C" void kernel_launch(void* const* d_in, const int* in_sizes, int n_in,
                              void* d_out, int out_size, void* d_ws, size_t ws_size,
                              hipStream_t stream) {
  const float* x_in   = (const float*)d_in[0];
  const float* ln_w   = (const float*)d_in[1];
  const float* w_up   = (const float*)d_in[2];
  const float* conv_w = (const float*)d_in[3];
  const float* conv_b = (const float*)d_in[4];
  const float* wq     = (const float*)d_in[5];
  const float* wk     = (const float*)d_in[6];
  const float* wv     = (const float*)d_in[7];
  const float* ig_w   = (const float*)d_in[8];
  const float* ig_b   = (const float*)d_in[9];
  const float* fg_w   = (const float*)d_in[10];
  const float* fg_b   = (const float*)d_in[11];
  const float* skip   = (const float*)d_in[12];
  const float* mhn_w  = (const float*)d_in[13];
  const float* w_down = (const float*)d_in[14];
  const float* post_w = (const float*)d_in[15];
  const float* proj_w = (const float*)d_in[16];
  const float* proj_b = (const float*)d_in[17];
  float* out = (float*)d_out;

  float* ws = (float*)d_ws;
  float* xbuf   = ws;                                   // ROWS*SE fp32
  float* part   = xbuf  + (size_t)ROWS*SE;              // ROWS*16 fp32
  __hip_bfloat16* cpart = (__hip_bfloat16*)(part + (size_t)ROWS*16); // KSPLIT*ROWS*SE bf16
  __hip_bfloat16* lnb   = cpart + (size_t)KSPLIT*ROWS*SE;
  __hip_bfloat16* upbuf = lnb   + (size_t)ROWS*SE;      // ROWS*2*SI bf16
  __hip_bfloat16* xact  = upbuf + (size_t)ROWS*2*SI;    // ROWS*SI bf16
  __hip_bfloat16* qb    = xact  + (size_t)ROWS*SI;      // ROWS*SI [b][h][s][d]
  __hip_bfloat16* kb    = qb    + (size_t)ROWS*SI;
  __hip_bfloat16* vb    = kb    + (size_t)ROWS*SI;
  __hip_bfloat16* habf  = vb    + (size_t)ROWS*SI;      // ROWS*SI
  __hip_bfloat16* wTup  = habf  + (size_t)ROWS*SI;      // 8 * 4096*1024
  __hip_bfloat16* wTdn  = wTup  + (size_t)8*SE*2*SI;    // 8 * 1024*2048

  hipMemcpyAsync(xbuf, x_in, (size_t)ROWS*SE*sizeof(float),
                 hipMemcpyDeviceToDevice, stream);

  // hoisted weight transposes (all 8 layers)
  transpose_bf16_kernel<<<dim3(128, 32, 8), 256, 0, stream>>>(w_up, wTup, SE, 2*SI);
  transpose_bf16_kernel<<<dim3(32, 64, 8), 256, 0, stream>>>(w_down, wTdn, SI, SE);

  for (int blk = 0; blk < 8; ++blk) {
    const float* lw   = ln_w   + (size_t)blk*SE;
    const float* cw   = conv_w + (size_t)blk*SI*4;
    const float* cb   = conv_b + (size_t)blk*SI;
    const float* wqb  = wq     + (size_t)blk*NHQ_*16;
    const float* wkb  = wk     + (size_t)blk*NHQ_*16;
    const float* wvb  = wv     + (size_t)blk*NHQ_*16;
    const float* igwb = ig_w   + (size_t)blk*3*SI*NHH;
    const float* igbb = ig_b   + (size_t)blk*NHH;
    const float* fgwb = fg_w   + (size_t)blk*3*SI*NHH;
    const float* fgbb = fg_b   + (size_t)blk*NHH;
    const float* skb  = skip   + (size_t)blk*SI;
    const float* mhb  = mhn_w  + (size_t)blk*SI;

    lnres_bf16_kernel<<<ROWS, 256, 0, stream>>>(
        xbuf, cpart, blk == 0 ? 0 : KSPLIT, lw, lnb);
    // up: [2944,1024] x [1024,4096] -> bf16  (736 blocks, %8==0 for swizzle)
    gemm_mfma<<<dim3(32, 23, 1), 256, 0, stream>>>(
        lnb, SE, wTup + (size_t)blk*SE*2*SI, SE, upbuf, 2*SI, SE, 0);
    conv_head_gate_kernel<<<(ROWS/4)*2, 256, 0, stream>>>(
        upbuf, cw, cb, wqb, wkb, wvb, igwb, fgwb, xact, qb, kb, vb, part);
    mlstm_mfma_kernel<<<SB*NHH, 512, 0, stream>>>(
        qb, kb, vb, part, igbb, fgbb, xact, upbuf, skb, mhb, habf);
    // down: [2944,2048] x [2048,1024] split-K=4 bf16 partials (184/slice, %8==0)
    gemm_mfma<<<dim3(8, 23, KSPLIT), 256, 0, stream>>>(
        habf, SI, wTdn + (size_t)blk*SI*SE, SI, cpart, SE, SI, (size_t)ROWS*SE);
  }
  proj_fused_kernel<<<SB*8, 256, 0, stream>>>(xbuf, cpart, post_w, proj_w, proj_b, out);
}

// Round 17
// 1187.890 us; speedup vs baseline: 1.1028x; 1.1028x over previous
//
#include <hip/hip_runtime.h>
#include <hip/hip_bf16.h>
#include <math.h>

// xLSTM block stack: 8 sequential blocks, then post-LN + projection.
// Round 16: R14 config (8-row chg + __expf) + gate weights hoisted out of
//           the row loop (24 float4 kept in registers; removes 7/8 of the
//           L2 load-latency exposure in the stall-dominated chg kernel).
//
#define SB   64            // batch
#define SS   46            // seq
#define SE   1024          // embed
#define SI   2048          // inner
#define ROWS (SB*SS)       // 2944
#define NHH  4             // mLSTM heads
#define DHH  512           // head dim
#define NHQ_ 512           // headwise 4x4 heads
#define OUTD 512
#define KSPLIT 4

typedef __attribute__((ext_vector_type(8))) short bf16x8;
typedef __attribute__((ext_vector_type(4))) short bf16x4;
typedef __attribute__((ext_vector_type(4))) float f32x4;

__device__ __forceinline__ void gload_lds16(const void* g, void* lds) {
  __builtin_amdgcn_global_load_lds(
      (const __attribute__((address_space(1))) unsigned int*)g,
      (__attribute__((address_space(3))) unsigned int*)lds, 16, 0, 0);
}

__device__ __forceinline__ float bf2f(short s) {
  union { unsigned int u; float f; } x;
  x.u = ((unsigned int)(unsigned short)s) << 16;
  return x.f;
}

__device__ __forceinline__ short f2bf_rne(float f) {
  union { float f; unsigned int u; } cv; cv.f = f;
  unsigned int lsb = (cv.u >> 16) & 1;
  cv.u += 0x7fff + lsb;
  return (short)(cv.u >> 16);
}

__device__ __forceinline__ float fexp(float x) { return __expf(x); }

// ---------------------------------------------------------------------------
// Residual-add (npart bf16 split-K partials) + LayerNorm -> bf16; xbuf updated.
__global__ __launch_bounds__(256) void lnres_bf16_kernel(
    float* __restrict__ xbuf, const __hip_bfloat16* __restrict__ parts, int npart,
    const float* __restrict__ w, __hip_bfloat16* __restrict__ out) {
  const int row = blockIdx.x;
  const int t = threadIdx.x;
  const int i0 = t * 4;
  float vals[4];
  {
    const float4 xv = *(const float4*)(xbuf + (size_t)row*SE + i0);
    vals[0] = xv.x; vals[1] = xv.y; vals[2] = xv.z; vals[3] = xv.w;
  }
  for (int p = 0; p < npart; ++p) {
    const bf16x4 pv = *(const bf16x4*)((const short*)parts +
        (size_t)p*ROWS*SE + (size_t)row*SE + i0);
#pragma unroll
    for (int j = 0; j < 4; ++j) vals[j] += bf2f(pv[j]);
  }
  float s1 = vals[0]+vals[1]+vals[2]+vals[3];
  float s2 = vals[0]*vals[0]+vals[1]*vals[1]+vals[2]*vals[2]+vals[3]*vals[3];
  if (npart) {
    float4 st = {vals[0], vals[1], vals[2], vals[3]};
    *(float4*)(xbuf + (size_t)row*SE + i0) = st;
  }
  __shared__ float r1[4], r2[4];
  for (int off = 32; off; off >>= 1) { s1 += __shfl_down(s1, off); s2 += __shfl_down(s2, off); }
  if ((t & 63) == 0) { r1[t >> 6] = s1; r2[t >> 6] = s2; }
  __syncthreads();
  s1 = r1[0]+r1[1]+r1[2]+r1[3];
  s2 = r2[0]+r2[1]+r2[2]+r2[3];
  const float mu = s1 * (1.f/SE);
  const float var = s2 * (1.f/SE) - mu*mu;
  const float rs = rsqrtf(var + 1e-5f);
  const float4 w4 = *(const float4*)(w + i0);
  const float wv[4] = {w4.x, w4.y, w4.z, w4.w};
  bf16x4 o;
#pragma unroll
  for (int j = 0; j < 4; ++j) o[j] = f2bf_rne((vals[j]-mu)*rs*wv[j]);
  *(bf16x4*)((short*)out + (size_t)row*SE + i0) = o;
}

// ---------------------------------------------------------------------------
// Transpose + convert (all 8 layers): W [z][K][N] fp32 -> Wt [z][N][K] bf16.
__global__ __launch_bounds__(256) void transpose_bf16_kernel(
    const float* __restrict__ W, __hip_bfloat16* __restrict__ Wt, int K, int N) {
  __shared__ float tile[32][33];
  const int z = blockIdx.z;
  const float* Wz = W + (size_t)z*K*N;
  __hip_bfloat16* Wtz = Wt + (size_t)z*K*N;
  const int k0 = blockIdx.y * 32, n0 = blockIdx.x * 32;
  const int tr = threadIdx.x >> 5;
  const int tc = threadIdx.x & 31;
#pragma unroll
  for (int i = 0; i < 4; ++i)
    tile[tr + i*8][tc] = Wz[(size_t)(k0 + tr + i*8)*N + n0 + tc];
  __syncthreads();
#pragma unroll
  for (int i = 0; i < 4; ++i)
    Wtz[(size_t)(n0 + tr + i*8)*K + k0 + tc] = __float2bfloat16(tile[tc][tr + i*8]);
}

// ---------------------------------------------------------------------------
// bf16 MFMA GEMM: C[M,N] = A[M,K_z] * Bt[N,K_z]^T over this z's K-slice.
// 128x128 tile, BK=32, 2-phase pipelined K-loop (counted vmcnt, raw barriers).
// XCD-aware bijective block swizzle (requires gx*gy % 8 == 0).
__global__ __launch_bounds__(256) void gemm_mfma(
    const __hip_bfloat16* __restrict__ A, int lda,
    const __hip_bfloat16* __restrict__ Bt, int ldb,
    __hip_bfloat16* __restrict__ Cv, int ldc, int K, size_t cstride) {
  __shared__ short As[2][128*32];
  __shared__ short Bs[2][128*32];
  const int t = threadIdx.x;
  const int lane = t & 63;
  const int w = t >> 6;
  const int wr = w >> 1, wc = w & 1;
  const int l15 = lane & 15, lg = lane >> 4;

  const int nxy = gridDim.x * gridDim.y;
  int flat = blockIdx.y * gridDim.x + blockIdx.x;
  const int cpx = nxy >> 3;
  flat = (flat & 7) * cpx + (flat >> 3);
  const int bx = flat % gridDim.x;
  const int by = flat / gridDim.x;

  const int row0 = by * 128, col0 = bx * 128;
  const int Kper = K / gridDim.z;
  const int kbeg = blockIdx.z * Kper, kend = kbeg + Kper;
  f32x4 acc[4][4];
#pragma unroll
  for (int m = 0; m < 4; ++m)
#pragma unroll
    for (int n = 0; n < 4; ++n) acc[m][n] = (f32x4){0.f,0.f,0.f,0.f};

  const int L0 = t*16;
  const int L1 = 4096 + t*16;
  const int r0s = L0 >> 6, k0s = (L0 & 63) >> 1;
  const int r1s = L1 >> 6, k1s = (L1 & 63) >> 1;

#define STAGE(buf, kk0)                                                        \
  do {                                                                         \
    gload_lds16(A  + (size_t)(row0 + r0s)*lda + (kk0) + k0s, (char*)As[buf] + L0); \
    gload_lds16(A  + (size_t)(row0 + r1s)*lda + (kk0) + k1s, (char*)As[buf] + L1); \
    gload_lds16(Bt + (size_t)(col0 + r0s)*ldb + (kk0) + k0s, (char*)Bs[buf] + L0); \
    gload_lds16(Bt + (size_t)(col0 + r1s)*ldb + (kk0) + k1s, (char*)Bs[buf] + L1); \
  } while (0)

  int cur = 0;
  STAGE(0, kbeg);
  for (int k0 = kbeg; k0 < kend; k0 += 32) {
    const bool haveNext = (k0 + 32 < kend);
    if (haveNext) {
      STAGE(cur ^ 1, k0 + 32);
      asm volatile("s_waitcnt vmcnt(4)" ::: "memory");
    } else {
      asm volatile("s_waitcnt vmcnt(0)" ::: "memory");
    }
    __builtin_amdgcn_sched_barrier(0);
    __builtin_amdgcn_s_barrier();
    bf16x8 af[4], bfr[4];
#pragma unroll
    for (int m = 0; m < 4; ++m)
      af[m] = *(const bf16x8*)&As[cur][(wr*64 + m*16 + l15)*32 + lg*8];
#pragma unroll
    for (int n = 0; n < 4; ++n)
      bfr[n] = *(const bf16x8*)&Bs[cur][(wc*64 + n*16 + l15)*32 + lg*8];
#pragma unroll
    for (int m = 0; m < 4; ++m)
#pragma unroll
      for (int n = 0; n < 4; ++n)
        acc[m][n] = __builtin_amdgcn_mfma_f32_16x16x32_bf16(af[m], bfr[n], acc[m][n], 0, 0, 0);
    asm volatile("s_waitcnt lgkmcnt(0)" ::: "memory");
    __builtin_amdgcn_sched_barrier(0);
    __builtin_amdgcn_s_barrier();
    cur ^= 1;
  }
#undef STAGE

  __hip_bfloat16* Cz = Cv + blockIdx.z * cstride;
#pragma unroll
  for (int m = 0; m < 4; ++m) {
#pragma unroll
    for (int n = 0; n < 4; ++n) {
      const int cc = col0 + wc*64 + n*16 + l15;
#pragma unroll
      for (int j = 0; j < 4; ++j) {
        const int rr = row0 + wr*64 + m*16 + lg*4 + j;
        Cz[(size_t)rr*ldc + cc] = __float2bfloat16(acc[m][n][j]);
      }
    }
  }
}

// ---------------------------------------------------------------------------
// Fused v6 (8 rows x 1024 channels per block; thread owns 4-channel group):
// causal conv(K=4)+SiLU -> xact bf16; headwise 4x4 q/k/v (thread-local) -> bf16;
// gate partials -> part[row][chunk*8+g].  Gate weights hoisted (registers).
__global__ __launch_bounds__(256) void conv_head_gate_kernel(
    const __hip_bfloat16* __restrict__ up, const float* __restrict__ cw,
    const float* __restrict__ cb,
    const float* __restrict__ wq, const float* __restrict__ wk,
    const float* __restrict__ wv,
    const float* __restrict__ igw, const float* __restrict__ fgw,
    __hip_bfloat16* __restrict__ xact,
    __hip_bfloat16* __restrict__ qb, __hip_bfloat16* __restrict__ kb,
    __hip_bfloat16* __restrict__ vb, float* __restrict__ part) {
  const int rblk  = blockIdx.x >> 1;       // 0..367 (8 rows each)
  const int chunk = blockIdx.x & 1;        // 0..1 (1024 channels each)
  const int r0 = rblk * 8;
  const int t = threadIdx.x;
  const int c4 = chunk*1024 + t*4;         // first of this thread's 4 channels
  const int lane = t & 63, wv_ = t >> 6;

  float wtap[4][4], bias[4];
#pragma unroll
  for (int j = 0; j < 4; ++j) {
    const float4 w4 = *(const float4*)(cw + (size_t)(c4 + j)*4);
    wtap[j][0] = w4.x; wtap[j][1] = w4.y; wtap[j][2] = w4.z; wtap[j][3] = w4.w;
  }
  {
    const float4 b4 = *(const float4*)(cb + c4);
    bias[0] = b4.x; bias[1] = b4.y; bias[2] = b4.z; bias[3] = b4.w;
  }
  const size_t hqo = (size_t)(c4 >> 2) * 16;
  float wqm[4][4], wkm[4][4], wvm[4][4];
#pragma unroll
  for (int o = 0; o < 4; ++o) {
    const float4 a = *(const float4*)(wq + hqo + o*4);
    const float4 b = *(const float4*)(wk + hqo + o*4);
    const float4 c = *(const float4*)(wv + hqo + o*4);
    wqm[o][0]=a.x; wqm[o][1]=a.y; wqm[o][2]=a.z; wqm[o][3]=a.w;
    wkm[o][0]=b.x; wkm[o][1]=b.y; wkm[o][2]=b.z; wkm[o][3]=b.w;
    wvm[o][0]=c.x; wvm[o][1]=c.y; wvm[o][2]=c.z; wvm[o][3]=c.w;
  }
  // gate weights hoisted: 24 float4 kept in registers across all 8 rows
  float4 wiqv[4], wikv[4], wivv[4], wfqv[4], wfkv[4], wfvv[4];
#pragma unroll
  for (int j = 0; j < 4; ++j) {
    wiqv[j] = *(const float4*)(igw + (size_t)(c4+j)*4);
    wikv[j] = *(const float4*)(igw + (size_t)(2048+c4+j)*4);
    wivv[j] = *(const float4*)(igw + (size_t)(4096+c4+j)*4);
    wfqv[j] = *(const float4*)(fgw + (size_t)(c4+j)*4);
    wfkv[j] = *(const float4*)(fgw + (size_t)(2048+c4+j)*4);
    wfvv[j] = *(const float4*)(fgw + (size_t)(4096+c4+j)*4);
  }

  // input rows r0-3 .. r0+7 (11 rows) as short4
  bf16x4 u[11];
#pragma unroll
  for (int i = 0; i < 11; ++i) {
    const int gr = r0 - 3 + i;
    u[i] = (gr >= 0) ? *(const bf16x4*)((const short*)up + (size_t)gr*(2*SI) + c4)
                     : (bf16x4){0,0,0,0};
  }

  __shared__ float red[8][4][8];   // [row][wave][gate]

  const int h = c4 >> 9, dd = c4 & 511;
#pragma unroll
  for (int rr = 0; rr < 8; ++rr) {
    const int row = r0 + rr;
    const int b = row / SS, s = row - (row / SS)*SS;
    float xa[4], xin[4];
#pragma unroll
    for (int j = 0; j < 4; ++j) {
      float acc = bias[j];
#pragma unroll
      for (int tap = 0; tap < 4; ++tap)
        if (s - 3 + tap >= 0) acc += bf2f(u[rr + tap][j]) * wtap[j][tap];
      xa[j] = acc / (1.f + fexp(-acc));
      xin[j] = bf2f(u[rr + 3][j]);
    }
    {
      bf16x4 xo;
#pragma unroll
      for (int j = 0; j < 4; ++j) xo[j] = f2bf_rne(xa[j]);
      *(bf16x4*)((short*)xact + (size_t)row*SI + c4) = xo;
    }
    float q[4], k[4], v[4];
#pragma unroll
    for (int o = 0; o < 4; ++o) {
      float aq = 0.f, ak = 0.f, av = 0.f;
#pragma unroll
      for (int d = 0; d < 4; ++d) {
        aq += xa[d] * wqm[o][d];
        ak += xa[d] * wkm[o][d];
        av += xin[d] * wvm[o][d];
      }
      q[o] = aq; k[o] = ak; v[o] = av;
    }
    const size_t dst = (((size_t)b*NHH + h)*SS + s)*DHH + dd;
    {
      bf16x4 qo, ko, vo;
#pragma unroll
      for (int j = 0; j < 4; ++j) {
        qo[j] = f2bf_rne(q[j]); ko[j] = f2bf_rne(k[j]); vo[j] = f2bf_rne(v[j]);
      }
      *(bf16x4*)((short*)qb + dst) = qo;
      *(bf16x4*)((short*)kb + dst) = ko;
      *(bf16x4*)((short*)vb + dst) = vo;
    }
    float a8[8] = {0,0,0,0,0,0,0,0};
#pragma unroll
    for (int j = 0; j < 4; ++j) {
      a8[0] += q[j]*wiqv[j].x + k[j]*wikv[j].x + v[j]*wivv[j].x;
      a8[1] += q[j]*wiqv[j].y + k[j]*wikv[j].y + v[j]*wivv[j].y;
      a8[2] += q[j]*wiqv[j].z + k[j]*wikv[j].z + v[j]*wivv[j].z;
      a8[3] += q[j]*wiqv[j].w + k[j]*wikv[j].w + v[j]*wivv[j].w;
      a8[4] += q[j]*wfqv[j].x + k[j]*wfkv[j].x + v[j]*wfvv[j].x;
      a8[5] += q[j]*wfqv[j].y + k[j]*wfkv[j].y + v[j]*wfvv[j].y;
      a8[6] += q[j]*wfqv[j].z + k[j]*wfkv[j].z + v[j]*wfvv[j].z;
      a8[7] += q[j]*wfqv[j].w + k[j]*wfkv[j].w + v[j]*wfvv[j].w;
    }
    for (int off = 32; off; off >>= 1)
#pragma unroll
      for (int g = 0; g < 8; ++g) a8[g] += __shfl_down(a8[g], off);
    if (lane == 0)
#pragma unroll
      for (int g = 0; g < 8; ++g) red[rr][wv_][g] = a8[g];
  }
  __syncthreads();
  if (t < 64) {
    const int rr = t >> 3, g = t & 7;
    part[(size_t)(r0 + rr)*16 + chunk*8 + g] =
        red[rr][0][g] + red[rr][1][g] + red[rr][2][g] + red[rr][3][g];
  }
}

// ---------------------------------------------------------------------------
// mLSTM per (b,head), 8 waves (512 thr): gate reduce + MFMA QK^T + parallel
// log-sigmoid scan (Kogge-Stone in wave 0) + VALU PV + fused multi-head
// norm/skip/gate epilogue -> habf bf16 [b*s][2048].
__global__ __launch_bounds__(512) void mlstm_mfma_kernel(
    const __hip_bfloat16* __restrict__ qb, const __hip_bfloat16* __restrict__ kb,
    const __hip_bfloat16* __restrict__ vb,
    const float* __restrict__ part,
    const float* __restrict__ igb, const float* __restrict__ fgb,
    const __hip_bfloat16* __restrict__ xact, const __hip_bfloat16* __restrict__ up,
    const float* __restrict__ skip, const float* __restrict__ mhn,
    __hip_bfloat16* __restrict__ habf) {
  const int bh = blockIdx.x;                 // b*4 + h
  const int b = bh >> 2, h = bh & 3;
  const int t = threadIdx.x;
  const int lane = t & 63, wid = t >> 6;     // wid 0..7
  const int l15 = lane & 15, lg = lane >> 4;

  __shared__ short QKs[2][48*264];
  __shared__ float Cs[46][48];
  __shared__ float cum[46], mmv[46], ips[46], fps[46], inv[46];
  short* Vs = &QKs[0][0];                    // alias: V [46][520] bf16

  if (t < SS) {
    const float* pr = part + (size_t)(b*SS + t)*16;
    float si = igb[h], sf = fgb[h];
#pragma unroll
    for (int ch = 0; ch < 2; ++ch) { si += pr[ch*8 + h]; sf += pr[ch*8 + 4 + h]; }
    ips[t] = si; fps[t] = sf;
  }

  int prs[2]; int np = 0;
  for (int p = wid; p < 9; p += 8) prs[np++] = p;
  f32x4 acc[2];
#pragma unroll
  for (int i = 0; i < 2; ++i) acc[i] = (f32x4){0.f,0.f,0.f,0.f};

  for (int ph = 0; ph < 2; ++ph) {
    __syncthreads();
    for (int i = t; i < 48*32; i += 512) {
      const int row = i >> 5, oc = i & 31;
      bf16x8 vq = {0,0,0,0,0,0,0,0}, vk = {0,0,0,0,0,0,0,0};
      if (row < SS) {
        const size_t src = ((size_t)bh*SS + row)*DHH + ph*256 + oc*8;
        vq = *(const bf16x8*)(qb + src);
        vk = *(const bf16x8*)(kb + src);
      }
      *(bf16x8*)&QKs[0][row*264 + oc*8] = vq;
      *(bf16x8*)&QKs[1][row*264 + oc*8] = vk;
    }
    __syncthreads();
#pragma unroll
    for (int kc = 0; kc < 8; ++kc) {
      for (int i = 0; i < np; ++i) {
        const int mt = prs[i] / 3, nt = prs[i] - 3*(prs[i]/3);
        const bf16x8 a = *(const bf16x8*)&QKs[0][(mt*16 + l15)*264 + kc*32 + lg*8];
        const bf16x8 bb = *(const bf16x8*)&QKs[1][(nt*16 + l15)*264 + kc*32 + lg*8];
        acc[i] = __builtin_amdgcn_mfma_f32_16x16x32_bf16(a, bb, acc[i], 0, 0, 0);
      }
    }
  }
  __syncthreads();
  // parallel log-sigmoid cumsum + running-max scan (wave 0, Kogge-Stone)
  if (wid == 0) {
    const int s = lane;
    float lf = 0.f;
    if (s < SS) {
      const float xv = fps[s];
      lf = fminf(xv, 0.f) - log1pf(expf(-fabsf(xv)));
    }
#pragma unroll
    for (int off = 1; off < 64; off <<= 1) {
      const float o = __shfl_up(lf, off);
      if (lane >= off) lf += o;
    }
    float e = (s < SS) ? (ips[s] - lf) : -INFINITY;
#pragma unroll
    for (int off = 1; off < 64; off <<= 1) {
      const float o = __shfl_up(e, off);
      if (lane >= off) e = fmaxf(e, o);
    }
    if (s < SS) { cum[s] = lf; mmv[s] = lf + e; }
  }
  for (int i = t; i < SS*64; i += 512) {
    const int row = i >> 6, oc = i & 63;
    *(bf16x8*)&Vs[row*520 + oc*8] =
        *(const bf16x8*)(vb + ((size_t)bh*SS + row)*DHH + oc*8);
  }
  __syncthreads();
  const float rsq = 0.04419417382415922f;
  for (int i = 0; i < np; ++i) {
    const int mt = prs[i] / 3, nt = prs[i] - 3*(prs[i]/3);
    const int s = nt*16 + l15;
    if (s < SS) {
#pragma unroll
      for (int j = 0; j < 4; ++j) {
        const int tt = mt*16 + lg*4 + j;
        if (tt < SS) {
          float wgt = 0.f;
          if (s <= tt) wgt = rsq * fexp(cum[tt] - cum[s] + ips[s] - mmv[tt]);
          Cs[tt][s] = acc[i][j] * wgt;
        }
      }
    }
  }
  __syncthreads();
  if (t < SS) {
    float ssum = 0.f;
    for (int s = 0; s <= t; ++s) ssum += Cs[t][s];
    inv[t] = 1.f / (fmaxf(fabsf(ssum), fexp(-mmv[t])) + 1e-6f);
  }
  __syncthreads();
  const int c0 = h*DHH + lane*8;
  for (int it = 0; it < 6; ++it) {
    const int tt = wid + it*8;
    if (tt >= SS) break;
    float a[8];
#pragma unroll
    for (int j = 0; j < 8; ++j) a[j] = 0.f;
    for (int s = 0; s <= tt; ++s) {
      const float c = Cs[tt][s];
      const bf16x8 v8 = *(const bf16x8*)&Vs[s*520 + lane*8];
#pragma unroll
      for (int j = 0; j < 8; ++j) a[j] += c * bf2f(v8[j]);
    }
    const float sc = inv[tt];
    float s1 = 0.f, s2 = 0.f;
#pragma unroll
    for (int j = 0; j < 8; ++j) { a[j] *= sc; s1 += a[j]; s2 += a[j]*a[j]; }
#pragma unroll
    for (int off = 1; off < 64; off <<= 1) {
      s1 += __shfl_xor(s1, off); s2 += __shfl_xor(s2, off);
    }
    const float mu = s1 * (1.f/512.f);
    const float var = s2 * (1.f/512.f) - mu*mu;
    const float rs = rsqrtf(var + 1e-5f);
    const int row = b*SS + tt;
    const bf16x8 xa8 = *(const bf16x8*)((const short*)xact + (size_t)row*SI + c0);
    const bf16x8 z8 = *(const bf16x8*)((const short*)up + (size_t)row*(2*SI) + SI + c0);
    const float4 mh0 = *(const float4*)(mhn + c0);
    const float4 mh1 = *(const float4*)(mhn + c0 + 4);
    const float4 sk0 = *(const float4*)(skip + c0);
    const float4 sk1 = *(const float4*)(skip + c0 + 4);
    const float mhv[8] = {mh0.x,mh0.y,mh0.z,mh0.w,mh1.x,mh1.y,mh1.z,mh1.w};
    const float skv[8] = {sk0.x,sk0.y,sk0.z,sk0.w,sk1.x,sk1.y,sk1.z,sk1.w};
    bf16x8 o8;
#pragma unroll
    for (int j = 0; j < 8; ++j) {
      const float hv = (a[j]-mu)*rs*mhv[j] + skv[j]*bf2f(xa8[j]);
      const float zv = bf2f(z8[j]);
      o8[j] = f2bf_rne(hv * (zv / (1.f + fexp(-zv))));
    }
    *(bf16x8*)((short*)habf + (size_t)row*SI + c0) = o8;
  }
}

// ---------------------------------------------------------------------------
// Fused post-LN (residual + bf16 split-K partials) + projection.
__global__ __launch_bounds__(256) void proj_fused_kernel(
    const float* __restrict__ xbuf, const __hip_bfloat16* __restrict__ parts,
    const float* __restrict__ w, const float* __restrict__ pw,
    const float* __restrict__ pb, float* __restrict__ out) {
  const int b = blockIdx.x >> 3;
  const int och = blockIdx.x & 7;
  const int row = b*SS + SS - 1;
  const int t = threadIdx.x;
  const int wv_ = t >> 6, lane = t & 63;
  const int i0 = t * 4;
  float vals[4];
  {
    const float4 xv = *(const float4*)(xbuf + (size_t)row*SE + i0);
    vals[0] = xv.x; vals[1] = xv.y; vals[2] = xv.z; vals[3] = xv.w;
  }
#pragma unroll
  for (int p = 0; p < KSPLIT; ++p) {
    const bf16x4 pv = *(const bf16x4*)((const short*)parts +
        (size_t)p*ROWS*SE + (size_t)row*SE + i0);
#pragma unroll
    for (int j = 0; j < 4; ++j) vals[j] += bf2f(pv[j]);
  }
  float s1 = vals[0]+vals[1]+vals[2]+vals[3];
  float s2 = vals[0]*vals[0]+vals[1]*vals[1]+vals[2]*vals[2]+vals[3]*vals[3];
  __shared__ float r1[4], r2[4];
  __shared__ float xs[SE];
  __shared__ float red[4][64];
  for (int off = 32; off; off >>= 1) { s1 += __shfl_down(s1, off); s2 += __shfl_down(s2, off); }
  if (lane == 0) { r1[wv_] = s1; r2[wv_] = s2; }
  __syncthreads();
  s1 = r1[0]+r1[1]+r1[2]+r1[3];
  s2 = r2[0]+r2[1]+r2[2]+r2[3];
  const float mu = s1 * (1.f/SE);
  const float var = s2 * (1.f/SE) - mu*mu;
  const float rs = rsqrtf(var + 1e-5f);
  {
    const float4 w4 = *(const float4*)(w + i0);
    const float wv4[4] = {w4.x, w4.y, w4.z, w4.w};
#pragma unroll
    for (int j = 0; j < 4; ++j) xs[i0 + j] = (vals[j]-mu)*rs*wv4[j];
  }
  __syncthreads();
  const int o = och*64 + lane;
  float acc = 0.f;
  const int kbeg = wv_*256;
#pragma unroll 8
  for (int k = kbeg; k < kbeg + 256; ++k)
    acc += xs[k] * pw[(size_t)k*OUTD + o];
  red[wv_][lane] = acc;
  __syncthreads();
  if (t < 64)
    out[(size_t)b*OUTD + och*64 + t] =
        red[0][t] + red[1][t] + red[2][t] + red[3][t] + pb[och*64 + t];
}

// ---------------------------------------------------------------------------
extern "C" void kernel_launch(void* const* d_in, const int* in_sizes, int n_in,
                              void* d_out, int out_size, void* d_ws, size_t ws_size,
                              hipStream_t stream) {
  const float* x_in   = (const float*)d_in[0];
  const float* ln_w   = (const float*)d_in[1];
  const float* w_up   = (const float*)d_in[2];
  const float* conv_w = (const float*)d_in[3];
  const float* conv_b = (const float*)d_in[4];
  const float* wq     = (const float*)d_in[5];
  const float* wk     = (const float*)d_in[6];
  const float* wv     = (const float*)d_in[7];
  const float* ig_w   = (const float*)d_in[8];
  const float* ig_b   = (const float*)d_in[9];
  const float* fg_w   = (const float*)d_in[10];
  const float* fg_b   = (const float*)d_in[11];
  const float* skip   = (const float*)d_in[12];
  const float* mhn_w  = (const float*)d_in[13];
  const float* w_down = (const float*)d_in[14];
  const float* post_w = (const float*)d_in[15];
  const float* proj_w = (const float*)d_in[16];
  const float* proj_b = (const float*)d_in[17];
  float* out = (float*)d_out;

  float* ws = (float*)d_ws;
  float* xbuf   = ws;                                   // ROWS*SE fp32
  float* part   = xbuf  + (size_t)ROWS*SE;              // ROWS*16 fp32
  __hip_bfloat16* cpart = (__hip_bfloat16*)(part + (size_t)ROWS*16); // KSPLIT*ROWS*SE bf16
  __hip_bfloat16* lnb   = cpart + (size_t)KSPLIT*ROWS*SE;
  __hip_bfloat16* upbuf = lnb   + (size_t)ROWS*SE;      // ROWS*2*SI bf16
  __hip_bfloat16* xact  = upbuf + (size_t)ROWS*2*SI;    // ROWS*SI bf16
  __hip_bfloat16* qb    = xact  + (size_t)ROWS*SI;      // ROWS*SI [b][h][s][d]
  __hip_bfloat16* kb    = qb    + (size_t)ROWS*SI;
  __hip_bfloat16* vb    = kb    + (size_t)ROWS*SI;
  __hip_bfloat16* habf  = vb    + (size_t)ROWS*SI;      // ROWS*SI
  __hip_bfloat16* wTup  = habf  + (size_t)ROWS*SI;      // 8 * 4096*1024
  __hip_bfloat16* wTdn  = wTup  + (size_t)8*SE*2*SI;    // 8 * 1024*2048

  hipMemcpyAsync(xbuf, x_in, (size_t)ROWS*SE*sizeof(float),
                 hipMemcpyDeviceToDevice, stream);

  // hoisted weight transposes (all 8 layers)
  transpose_bf16_kernel<<<dim3(128, 32, 8), 256, 0, stream>>>(w_up, wTup, SE, 2*SI);
  transpose_bf16_kernel<<<dim3(32, 64, 8), 256, 0, stream>>>(w_down, wTdn, SI, SE);

  for (int blk = 0; blk < 8; ++blk) {
    const float* lw   = ln_w   + (size_t)blk*SE;
    const float* cw   = conv_w + (size_t)blk*SI*4;
    const float* cb   = conv_b + (size_t)blk*SI;
    const float* wqb  = wq     + (size_t)blk*NHQ_*16;
    const float* wkb  = wk     + (size_t)blk*NHQ_*16;
    const float* wvb  = wv     + (size_t)blk*NHQ_*16;
    const float* igwb = ig_w   + (size_t)blk*3*SI*NHH;
    const float* igbb = ig_b   + (size_t)blk*NHH;
    const float* fgwb = fg_w   + (size_t)blk*3*SI*NHH;
    const float* fgbb = fg_b   + (size_t)blk*NHH;
    const float* skb  = skip   + (size_t)blk*SI;
    const float* mhb  = mhn_w  + (size_t)blk*SI;

    lnres_bf16_kernel<<<ROWS, 256, 0, stream>>>(
        xbuf, cpart, blk == 0 ? 0 : KSPLIT, lw, lnb);
    // up: [2944,1024] x [1024,4096] -> bf16  (736 blocks, %8==0 for swizzle)
    gemm_mfma<<<dim3(32, 23, 1), 256, 0, stream>>>(
        lnb, SE, wTup + (size_t)blk*SE*2*SI, SE, upbuf, 2*SI, SE, 0);
    conv_head_gate_kernel<<<(ROWS/8)*2, 256, 0, stream>>>(
        upbuf, cw, cb, wqb, wkb, wvb, igwb, fgwb, xact, qb, kb, vb, part);
    mlstm_mfma_kernel<<<SB*NHH, 512, 0, stream>>>(
        qb, kb, vb, part, igbb, fgbb, xact, upbuf, skb, mhb, habf);
    // down: [2944,2048] x [2048,1024] split-K=4 bf16 partials (184/slice, %8==0)
    gemm_mfma<<<dim3(8, 23, KSPLIT), 256, 0, stream>>>(
        habf, SI, wTdn + (size_t)blk*SI*SE, SI, cpart, SE, SI, (size_t)ROWS*SE);
  }
  proj_fused_kernel<<<SB*8, 256, 0, stream>>>(xbuf, cpart, post_w, proj_w, proj_b, out);
}

// Round 18
// 1104.308 us; speedup vs baseline: 1.1862x; 1.0757x over previous
//
#include <hip/hip_runtime.h>
#include <hip/hip_bf16.h>
#include <math.h>

// xLSTM block stack: 8 sequential blocks, then post-LN + projection.
// Round 17: gate weights algebraically folded through the headwise 4x4 maps
//           (GA/GV/FA/FV per channel): chg computes gates from xa/xin directly.
//           16 hoisted float4 instead of 24 -> VGPR<=128, occupancy restored.
//
#define SB   64            // batch
#define SS   46            // seq
#define SE   1024          // embed
#define SI   2048          // inner
#define ROWS (SB*SS)       // 2944
#define NHH  4             // mLSTM heads
#define DHH  512           // head dim
#define NHQ_ 512           // headwise 4x4 heads
#define OUTD 512
#define KSPLIT 4

typedef __attribute__((ext_vector_type(8))) short bf16x8;
typedef __attribute__((ext_vector_type(4))) short bf16x4;
typedef __attribute__((ext_vector_type(4))) float f32x4;

__device__ __forceinline__ void gload_lds16(const void* g, void* lds) {
  __builtin_amdgcn_global_load_lds(
      (const __attribute__((address_space(1))) unsigned int*)g,
      (__attribute__((address_space(3))) unsigned int*)lds, 16, 0, 0);
}

__device__ __forceinline__ float bf2f(short s) {
  union { unsigned int u; float f; } x;
  x.u = ((unsigned int)(unsigned short)s) << 16;
  return x.f;
}

__device__ __forceinline__ short f2bf_rne(float f) {
  union { float f; unsigned int u; } cv; cv.f = f;
  unsigned int lsb = (cv.u >> 16) & 1;
  cv.u += 0x7fff + lsb;
  return (short)(cv.u >> 16);
}

__device__ __forceinline__ float fexp(float x) { return __expf(x); }

// ---------------------------------------------------------------------------
// Fold gate weights through headwise 4x4 maps (all 8 layers).
// gfold layout per layer: [GA|GV|FA|FV][2048][4] fp32 (4*8192 floats).
__global__ __launch_bounds__(256) void fold_gate_kernel(
    const float* __restrict__ wq, const float* __restrict__ wk,
    const float* __restrict__ wv, const float* __restrict__ igw,
    const float* __restrict__ fgw, float* __restrict__ gfold) {
  const int z = blockIdx.y;
  const int c = blockIdx.x * 256 + threadIdx.x;   // 0..2047
  const int hq = c >> 2, d = c & 3;
  const float* wqz = wq + (size_t)z*NHQ_*16;
  const float* wkz = wk + (size_t)z*NHQ_*16;
  const float* wvz = wv + (size_t)z*NHQ_*16;
  const float* igz = igw + (size_t)z*3*SI*NHH;
  const float* fgz = fgw + (size_t)z*3*SI*NHH;
  float ga[4] = {0,0,0,0}, gv[4] = {0,0,0,0};
  float fa[4] = {0,0,0,0}, fv[4] = {0,0,0,0};
#pragma unroll
  for (int o = 0; o < 4; ++o) {
    const float q = wqz[(size_t)hq*16 + o*4 + d];
    const float k = wkz[(size_t)hq*16 + o*4 + d];
    const float v = wvz[(size_t)hq*16 + o*4 + d];
    const float4 iq = *(const float4*)(igz + (size_t)(hq*4 + o)*4);
    const float4 ik = *(const float4*)(igz + (size_t)(2048 + hq*4 + o)*4);
    const float4 iv = *(const float4*)(igz + (size_t)(4096 + hq*4 + o)*4);
    const float4 fq = *(const float4*)(fgz + (size_t)(hq*4 + o)*4);
    const float4 fk = *(const float4*)(fgz + (size_t)(2048 + hq*4 + o)*4);
    const float4 fv4 = *(const float4*)(fgz + (size_t)(4096 + hq*4 + o)*4);
    ga[0] += q*iq.x + k*ik.x; ga[1] += q*iq.y + k*ik.y;
    ga[2] += q*iq.z + k*ik.z; ga[3] += q*iq.w + k*ik.w;
    gv[0] += v*iv.x; gv[1] += v*iv.y; gv[2] += v*iv.z; gv[3] += v*iv.w;
    fa[0] += q*fq.x + k*fk.x; fa[1] += q*fq.y + k*fk.y;
    fa[2] += q*fq.z + k*fk.z; fa[3] += q*fq.w + k*fk.w;
    fv[0] += v*fv4.x; fv[1] += v*fv4.y; fv[2] += v*fv4.z; fv[3] += v*fv4.w;
  }
  float* gz = gfold + (size_t)z*4*8192;
  *(float4*)(gz + 0*8192 + c*4) = (float4){ga[0],ga[1],ga[2],ga[3]};
  *(float4*)(gz + 1*8192 + c*4) = (float4){gv[0],gv[1],gv[2],gv[3]};
  *(float4*)(gz + 2*8192 + c*4) = (float4){fa[0],fa[1],fa[2],fa[3]};
  *(float4*)(gz + 3*8192 + c*4) = (float4){fv[0],fv[1],fv[2],fv[3]};
}

// ---------------------------------------------------------------------------
// Residual-add (npart bf16 split-K partials) + LayerNorm -> bf16; xbuf updated.
__global__ __launch_bounds__(256) void lnres_bf16_kernel(
    float* __restrict__ xbuf, const __hip_bfloat16* __restrict__ parts, int npart,
    const float* __restrict__ w, __hip_bfloat16* __restrict__ out) {
  const int row = blockIdx.x;
  const int t = threadIdx.x;
  const int i0 = t * 4;
  float vals[4];
  {
    const float4 xv = *(const float4*)(xbuf + (size_t)row*SE + i0);
    vals[0] = xv.x; vals[1] = xv.y; vals[2] = xv.z; vals[3] = xv.w;
  }
  for (int p = 0; p < npart; ++p) {
    const bf16x4 pv = *(const bf16x4*)((const short*)parts +
        (size_t)p*ROWS*SE + (size_t)row*SE + i0);
#pragma unroll
    for (int j = 0; j < 4; ++j) vals[j] += bf2f(pv[j]);
  }
  float s1 = vals[0]+vals[1]+vals[2]+vals[3];
  float s2 = vals[0]*vals[0]+vals[1]*vals[1]+vals[2]*vals[2]+vals[3]*vals[3];
  if (npart) {
    float4 st = {vals[0], vals[1], vals[2], vals[3]};
    *(float4*)(xbuf + (size_t)row*SE + i0) = st;
  }
  __shared__ float r1[4], r2[4];
  for (int off = 32; off; off >>= 1) { s1 += __shfl_down(s1, off); s2 += __shfl_down(s2, off); }
  if ((t & 63) == 0) { r1[t >> 6] = s1; r2[t >> 6] = s2; }
  __syncthreads();
  s1 = r1[0]+r1[1]+r1[2]+r1[3];
  s2 = r2[0]+r2[1]+r2[2]+r2[3];
  const float mu = s1 * (1.f/SE);
  const float var = s2 * (1.f/SE) - mu*mu;
  const float rs = rsqrtf(var + 1e-5f);
  const float4 w4 = *(const float4*)(w + i0);
  const float wv[4] = {w4.x, w4.y, w4.z, w4.w};
  bf16x4 o;
#pragma unroll
  for (int j = 0; j < 4; ++j) o[j] = f2bf_rne((vals[j]-mu)*rs*wv[j]);
  *(bf16x4*)((short*)out + (size_t)row*SE + i0) = o;
}

// ---------------------------------------------------------------------------
// Transpose + convert (all 8 layers): W [z][K][N] fp32 -> Wt [z][N][K] bf16.
__global__ __launch_bounds__(256) void transpose_bf16_kernel(
    const float* __restrict__ W, __hip_bfloat16* __restrict__ Wt, int K, int N) {
  __shared__ float tile[32][33];
  const int z = blockIdx.z;
  const float* Wz = W + (size_t)z*K*N;
  __hip_bfloat16* Wtz = Wt + (size_t)z*K*N;
  const int k0 = blockIdx.y * 32, n0 = blockIdx.x * 32;
  const int tr = threadIdx.x >> 5;
  const int tc = threadIdx.x & 31;
#pragma unroll
  for (int i = 0; i < 4; ++i)
    tile[tr + i*8][tc] = Wz[(size_t)(k0 + tr + i*8)*N + n0 + tc];
  __syncthreads();
#pragma unroll
  for (int i = 0; i < 4; ++i)
    Wtz[(size_t)(n0 + tr + i*8)*K + k0 + tc] = __float2bfloat16(tile[tc][tr + i*8]);
}

// ---------------------------------------------------------------------------
// bf16 MFMA GEMM: C[M,N] = A[M,K_z] * Bt[N,K_z]^T over this z's K-slice.
// 128x128 tile, BK=32, 2-phase pipelined K-loop (counted vmcnt, raw barriers).
// XCD-aware bijective block swizzle (requires gx*gy % 8 == 0).
__global__ __launch_bounds__(256) void gemm_mfma(
    const __hip_bfloat16* __restrict__ A, int lda,
    const __hip_bfloat16* __restrict__ Bt, int ldb,
    __hip_bfloat16* __restrict__ Cv, int ldc, int K, size_t cstride) {
  __shared__ short As[2][128*32];
  __shared__ short Bs[2][128*32];
  const int t = threadIdx.x;
  const int lane = t & 63;
  const int w = t >> 6;
  const int wr = w >> 1, wc = w & 1;
  const int l15 = lane & 15, lg = lane >> 4;

  const int nxy = gridDim.x * gridDim.y;
  int flat = blockIdx.y * gridDim.x + blockIdx.x;
  const int cpx = nxy >> 3;
  flat = (flat & 7) * cpx + (flat >> 3);
  const int bx = flat % gridDim.x;
  const int by = flat / gridDim.x;

  const int row0 = by * 128, col0 = bx * 128;
  const int Kper = K / gridDim.z;
  const int kbeg = blockIdx.z * Kper, kend = kbeg + Kper;
  f32x4 acc[4][4];
#pragma unroll
  for (int m = 0; m < 4; ++m)
#pragma unroll
    for (int n = 0; n < 4; ++n) acc[m][n] = (f32x4){0.f,0.f,0.f,0.f};

  const int L0 = t*16;
  const int L1 = 4096 + t*16;
  const int r0s = L0 >> 6, k0s = (L0 & 63) >> 1;
  const int r1s = L1 >> 6, k1s = (L1 & 63) >> 1;

#define STAGE(buf, kk0)                                                        \
  do {                                                                         \
    gload_lds16(A  + (size_t)(row0 + r0s)*lda + (kk0) + k0s, (char*)As[buf] + L0); \
    gload_lds16(A  + (size_t)(row0 + r1s)*lda + (kk0) + k1s, (char*)As[buf] + L1); \
    gload_lds16(Bt + (size_t)(col0 + r0s)*ldb + (kk0) + k0s, (char*)Bs[buf] + L0); \
    gload_lds16(Bt + (size_t)(col0 + r1s)*ldb + (kk0) + k1s, (char*)Bs[buf] + L1); \
  } while (0)

  int cur = 0;
  STAGE(0, kbeg);
  for (int k0 = kbeg; k0 < kend; k0 += 32) {
    const bool haveNext = (k0 + 32 < kend);
    if (haveNext) {
      STAGE(cur ^ 1, k0 + 32);
      asm volatile("s_waitcnt vmcnt(4)" ::: "memory");
    } else {
      asm volatile("s_waitcnt vmcnt(0)" ::: "memory");
    }
    __builtin_amdgcn_sched_barrier(0);
    __builtin_amdgcn_s_barrier();
    bf16x8 af[4], bfr[4];
#pragma unroll
    for (int m = 0; m < 4; ++m)
      af[m] = *(const bf16x8*)&As[cur][(wr*64 + m*16 + l15)*32 + lg*8];
#pragma unroll
    for (int n = 0; n < 4; ++n)
      bfr[n] = *(const bf16x8*)&Bs[cur][(wc*64 + n*16 + l15)*32 + lg*8];
#pragma unroll
    for (int m = 0; m < 4; ++m)
#pragma unroll
      for (int n = 0; n < 4; ++n)
        acc[m][n] = __builtin_amdgcn_mfma_f32_16x16x32_bf16(af[m], bfr[n], acc[m][n], 0, 0, 0);
    asm volatile("s_waitcnt lgkmcnt(0)" ::: "memory");
    __builtin_amdgcn_sched_barrier(0);
    __builtin_amdgcn_s_barrier();
    cur ^= 1;
  }
#undef STAGE

  __hip_bfloat16* Cz = Cv + blockIdx.z * cstride;
#pragma unroll
  for (int m = 0; m < 4; ++m) {
#pragma unroll
    for (int n = 0; n < 4; ++n) {
      const int cc = col0 + wc*64 + n*16 + l15;
#pragma unroll
      for (int j = 0; j < 4; ++j) {
        const int rr = row0 + wr*64 + m*16 + lg*4 + j;
        Cz[(size_t)rr*ldc + cc] = __float2bfloat16(acc[m][n][j]);
      }
    }
  }
}

// ---------------------------------------------------------------------------
// Fused v7 (8 rows x 1024 channels per block; thread owns 4-channel group):
// causal conv(K=4)+SiLU -> xact bf16; headwise 4x4 q/k/v (thread-local) -> bf16;
// gate partials from folded weights (xa/xin directly) -> part[row][chunk*8+g].
__global__ __launch_bounds__(256) void conv_head_gate_kernel(
    const __hip_bfloat16* __restrict__ up, const float* __restrict__ cw,
    const float* __restrict__ cb,
    const float* __restrict__ wq, const float* __restrict__ wk,
    const float* __restrict__ wv,
    const float* __restrict__ gfold,
    __hip_bfloat16* __restrict__ xact,
    __hip_bfloat16* __restrict__ qb, __hip_bfloat16* __restrict__ kb,
    __hip_bfloat16* __restrict__ vb, float* __restrict__ part) {
  const int rblk  = blockIdx.x >> 1;       // 0..367 (8 rows each)
  const int chunk = blockIdx.x & 1;        // 0..1 (1024 channels each)
  const int r0 = rblk * 8;
  const int t = threadIdx.x;
  const int c4 = chunk*1024 + t*4;         // first of this thread's 4 channels
  const int lane = t & 63, wv_ = t >> 6;

  float wtap[4][4], bias[4];
#pragma unroll
  for (int j = 0; j < 4; ++j) {
    const float4 w4 = *(const float4*)(cw + (size_t)(c4 + j)*4);
    wtap[j][0] = w4.x; wtap[j][1] = w4.y; wtap[j][2] = w4.z; wtap[j][3] = w4.w;
  }
  {
    const float4 b4 = *(const float4*)(cb + c4);
    bias[0] = b4.x; bias[1] = b4.y; bias[2] = b4.z; bias[3] = b4.w;
  }
  const size_t hqo = (size_t)(c4 >> 2) * 16;
  float wqm[4][4], wkm[4][4], wvm[4][4];
#pragma unroll
  for (int o = 0; o < 4; ++o) {
    const float4 a = *(const float4*)(wq + hqo + o*4);
    const float4 b = *(const float4*)(wk + hqo + o*4);
    const float4 c = *(const float4*)(wv + hqo + o*4);
    wqm[o][0]=a.x; wqm[o][1]=a.y; wqm[o][2]=a.z; wqm[o][3]=a.w;
    wkm[o][0]=b.x; wkm[o][1]=b.y; wkm[o][2]=b.z; wkm[o][3]=b.w;
    wvm[o][0]=c.x; wvm[o][1]=c.y; wvm[o][2]=c.z; wvm[o][3]=c.w;
  }
  // folded gate weights: 16 float4 in registers
  float4 gav[4], gvv[4], fav[4], fvv[4];
#pragma unroll
  for (int j = 0; j < 4; ++j) {
    gav[j] = *(const float4*)(gfold + 0*8192 + (size_t)(c4+j)*4);
    gvv[j] = *(const float4*)(gfold + 1*8192 + (size_t)(c4+j)*4);
    fav[j] = *(const float4*)(gfold + 2*8192 + (size_t)(c4+j)*4);
    fvv[j] = *(const float4*)(gfold + 3*8192 + (size_t)(c4+j)*4);
  }

  // input rows r0-3 .. r0+7 (11 rows) as short4
  bf16x4 u[11];
#pragma unroll
  for (int i = 0; i < 11; ++i) {
    const int gr = r0 - 3 + i;
    u[i] = (gr >= 0) ? *(const bf16x4*)((const short*)up + (size_t)gr*(2*SI) + c4)
                     : (bf16x4){0,0,0,0};
  }

  __shared__ float red[8][4][8];   // [row][wave][gate]

  const int h = c4 >> 9, dd = c4 & 511;
#pragma unroll
  for (int rr = 0; rr < 8; ++rr) {
    const int row = r0 + rr;
    const int b = row / SS, s = row - (row / SS)*SS;
    float xa[4], xin[4];
#pragma unroll
    for (int j = 0; j < 4; ++j) {
      float acc = bias[j];
#pragma unroll
      for (int tap = 0; tap < 4; ++tap)
        if (s - 3 + tap >= 0) acc += bf2f(u[rr + tap][j]) * wtap[j][tap];
      xa[j] = acc / (1.f + fexp(-acc));
      xin[j] = bf2f(u[rr + 3][j]);
    }
    {
      bf16x4 xo;
#pragma unroll
      for (int j = 0; j < 4; ++j) xo[j] = f2bf_rne(xa[j]);
      *(bf16x4*)((short*)xact + (size_t)row*SI + c4) = xo;
    }
    float q[4], k[4], v[4];
#pragma unroll
    for (int o = 0; o < 4; ++o) {
      float aq = 0.f, ak = 0.f, av = 0.f;
#pragma unroll
      for (int d = 0; d < 4; ++d) {
        aq += xa[d] * wqm[o][d];
        ak += xa[d] * wkm[o][d];
        av += xin[d] * wvm[o][d];
      }
      q[o] = aq; k[o] = ak; v[o] = av;
    }
    const size_t dst = (((size_t)b*NHH + h)*SS + s)*DHH + dd;
    {
      bf16x4 qo, ko, vo;
#pragma unroll
      for (int j = 0; j < 4; ++j) {
        qo[j] = f2bf_rne(q[j]); ko[j] = f2bf_rne(k[j]); vo[j] = f2bf_rne(v[j]);
      }
      *(bf16x4*)((short*)qb + dst) = qo;
      *(bf16x4*)((short*)kb + dst) = ko;
      *(bf16x4*)((short*)vb + dst) = vo;
    }
    // gate partials from folded weights (xa, xin directly)
    float a8[8] = {0,0,0,0,0,0,0,0};
#pragma unroll
    for (int j = 0; j < 4; ++j) {
      a8[0] += xa[j]*gav[j].x + xin[j]*gvv[j].x;
      a8[1] += xa[j]*gav[j].y + xin[j]*gvv[j].y;
      a8[2] += xa[j]*gav[j].z + xin[j]*gvv[j].z;
      a8[3] += xa[j]*gav[j].w + xin[j]*gvv[j].w;
      a8[4] += xa[j]*fav[j].x + xin[j]*fvv[j].x;
      a8[5] += xa[j]*fav[j].y + xin[j]*fvv[j].y;
      a8[6] += xa[j]*fav[j].z + xin[j]*fvv[j].z;
      a8[7] += xa[j]*fav[j].w + xin[j]*fvv[j].w;
    }
    for (int off = 32; off; off >>= 1)
#pragma unroll
      for (int g = 0; g < 8; ++g) a8[g] += __shfl_down(a8[g], off);
    if (lane == 0)
#pragma unroll
      for (int g = 0; g < 8; ++g) red[rr][wv_][g] = a8[g];
  }
  __syncthreads();
  if (t < 64) {
    const int rr = t >> 3, g = t & 7;
    part[(size_t)(r0 + rr)*16 + chunk*8 + g] =
        red[rr][0][g] + red[rr][1][g] + red[rr][2][g] + red[rr][3][g];
  }
}

// ---------------------------------------------------------------------------
// mLSTM per (b,head), 8 waves (512 thr): gate reduce + MFMA QK^T + parallel
// log-sigmoid scan (Kogge-Stone in wave 0) + VALU PV + fused multi-head
// norm/skip/gate epilogue -> habf bf16 [b*s][2048].
__global__ __launch_bounds__(512) void mlstm_mfma_kernel(
    const __hip_bfloat16* __restrict__ qb, const __hip_bfloat16* __restrict__ kb,
    const __hip_bfloat16* __restrict__ vb,
    const float* __restrict__ part,
    const float* __restrict__ igb, const float* __restrict__ fgb,
    const __hip_bfloat16* __restrict__ xact, const __hip_bfloat16* __restrict__ up,
    const float* __restrict__ skip, const float* __restrict__ mhn,
    __hip_bfloat16* __restrict__ habf) {
  const int bh = blockIdx.x;                 // b*4 + h
  const int b = bh >> 2, h = bh & 3;
  const int t = threadIdx.x;
  const int lane = t & 63, wid = t >> 6;     // wid 0..7
  const int l15 = lane & 15, lg = lane >> 4;

  __shared__ short QKs[2][48*264];
  __shared__ float Cs[46][48];
  __shared__ float cum[46], mmv[46], ips[46], fps[46], inv[46];
  short* Vs = &QKs[0][0];                    // alias: V [46][520] bf16

  if (t < SS) {
    const float* pr = part + (size_t)(b*SS + t)*16;
    float si = igb[h], sf = fgb[h];
#pragma unroll
    for (int ch = 0; ch < 2; ++ch) { si += pr[ch*8 + h]; sf += pr[ch*8 + 4 + h]; }
    ips[t] = si; fps[t] = sf;
  }

  int prs[2]; int np = 0;
  for (int p = wid; p < 9; p += 8) prs[np++] = p;
  f32x4 acc[2];
#pragma unroll
  for (int i = 0; i < 2; ++i) acc[i] = (f32x4){0.f,0.f,0.f,0.f};

  for (int ph = 0; ph < 2; ++ph) {
    __syncthreads();
    for (int i = t; i < 48*32; i += 512) {
      const int row = i >> 5, oc = i & 31;
      bf16x8 vq = {0,0,0,0,0,0,0,0}, vk = {0,0,0,0,0,0,0,0};
      if (row < SS) {
        const size_t src = ((size_t)bh*SS + row)*DHH + ph*256 + oc*8;
        vq = *(const bf16x8*)(qb + src);
        vk = *(const bf16x8*)(kb + src);
      }
      *(bf16x8*)&QKs[0][row*264 + oc*8] = vq;
      *(bf16x8*)&QKs[1][row*264 + oc*8] = vk;
    }
    __syncthreads();
#pragma unroll
    for (int kc = 0; kc < 8; ++kc) {
      for (int i = 0; i < np; ++i) {
        const int mt = prs[i] / 3, nt = prs[i] - 3*(prs[i]/3);
        const bf16x8 a = *(const bf16x8*)&QKs[0][(mt*16 + l15)*264 + kc*32 + lg*8];
        const bf16x8 bb = *(const bf16x8*)&QKs[1][(nt*16 + l15)*264 + kc*32 + lg*8];
        acc[i] = __builtin_amdgcn_mfma_f32_16x16x32_bf16(a, bb, acc[i], 0, 0, 0);
      }
    }
  }
  __syncthreads();
  // parallel log-sigmoid cumsum + running-max scan (wave 0, Kogge-Stone)
  if (wid == 0) {
    const int s = lane;
    float lf = 0.f;
    if (s < SS) {
      const float xv = fps[s];
      lf = fminf(xv, 0.f) - log1pf(expf(-fabsf(xv)));
    }
#pragma unroll
    for (int off = 1; off < 64; off <<= 1) {
      const float o = __shfl_up(lf, off);
      if (lane >= off) lf += o;
    }
    float e = (s < SS) ? (ips[s] - lf) : -INFINITY;
#pragma unroll
    for (int off = 1; off < 64; off <<= 1) {
      const float o = __shfl_up(e, off);
      if (lane >= off) e = fmaxf(e, o);
    }
    if (s < SS) { cum[s] = lf; mmv[s] = lf + e; }
  }
  for (int i = t; i < SS*64; i += 512) {
    const int row = i >> 6, oc = i & 63;
    *(bf16x8*)&Vs[row*520 + oc*8] =
        *(const bf16x8*)(vb + ((size_t)bh*SS + row)*DHH + oc*8);
  }
  __syncthreads();
  const float rsq = 0.04419417382415922f;
  for (int i = 0; i < np; ++i) {
    const int mt = prs[i] / 3, nt = prs[i] - 3*(prs[i]/3);
    const int s = nt*16 + l15;
    if (s < SS) {
#pragma unroll
      for (int j = 0; j < 4; ++j) {
        const int tt = mt*16 + lg*4 + j;
        if (tt < SS) {
          float wgt = 0.f;
          if (s <= tt) wgt = rsq * fexp(cum[tt] - cum[s] + ips[s] - mmv[tt]);
          Cs[tt][s] = acc[i][j] * wgt;
        }
      }
    }
  }
  __syncthreads();
  if (t < SS) {
    float ssum = 0.f;
    for (int s = 0; s <= t; ++s) ssum += Cs[t][s];
    inv[t] = 1.f / (fmaxf(fabsf(ssum), fexp(-mmv[t])) + 1e-6f);
  }
  __syncthreads();
  const int c0 = h*DHH + lane*8;
  for (int it = 0; it < 6; ++it) {
    const int tt = wid + it*8;
    if (tt >= SS) break;
    float a[8];
#pragma unroll
    for (int j = 0; j < 8; ++j) a[j] = 0.f;
    for (int s = 0; s <= tt; ++s) {
      const float c = Cs[tt][s];
      const bf16x8 v8 = *(const bf16x8*)&Vs[s*520 + lane*8];
#pragma unroll
      for (int j = 0; j < 8; ++j) a[j] += c * bf2f(v8[j]);
    }
    const float sc = inv[tt];
    float s1 = 0.f, s2 = 0.f;
#pragma unroll
    for (int j = 0; j < 8; ++j) { a[j] *= sc; s1 += a[j]; s2 += a[j]*a[j]; }
#pragma unroll
    for (int off = 1; off < 64; off <<= 1) {
      s1 += __shfl_xor(s1, off); s2 += __shfl_xor(s2, off);
    }
    const float mu = s1 * (1.f/512.f);
    const float var = s2 * (1.f/512.f) - mu*mu;
    const float rs = rsqrtf(var + 1e-5f);
    const int row = b*SS + tt;
    const bf16x8 xa8 = *(const bf16x8*)((const short*)xact + (size_t)row*SI + c0);
    const bf16x8 z8 = *(const bf16x8*)((const short*)up + (size_t)row*(2*SI) + SI + c0);
    const float4 mh0 = *(const float4*)(mhn + c0);
    const float4 mh1 = *(const float4*)(mhn + c0 + 4);
    const float4 sk0 = *(const float4*)(skip + c0);
    const float4 sk1 = *(const float4*)(skip + c0 + 4);
    const float mhv[8] = {mh0.x,mh0.y,mh0.z,mh0.w,mh1.x,mh1.y,mh1.z,mh1.w};
    const float skv[8] = {sk0.x,sk0.y,sk0.z,sk0.w,sk1.x,sk1.y,sk1.z,sk1.w};
    bf16x8 o8;
#pragma unroll
    for (int j = 0; j < 8; ++j) {
      const float hv = (a[j]-mu)*rs*mhv[j] + skv[j]*bf2f(xa8[j]);
      const float zv = bf2f(z8[j]);
      o8[j] = f2bf_rne(hv * (zv / (1.f + fexp(-zv))));
    }
    *(bf16x8*)((short*)habf + (size_t)row*SI + c0) = o8;
  }
}

// ---------------------------------------------------------------------------
// Fused post-LN (residual + bf16 split-K partials) + projection.
__global__ __launch_bounds__(256) void proj_fused_kernel(
    const float* __restrict__ xbuf, const __hip_bfloat16* __restrict__ parts,
    const float* __restrict__ w, const float* __restrict__ pw,
    const float* __restrict__ pb, float* __restrict__ out) {
  const int b = blockIdx.x >> 3;
  const int och = blockIdx.x & 7;
  const int row = b*SS + SS - 1;
  const int t = threadIdx.x;
  const int wv_ = t >> 6, lane = t & 63;
  const int i0 = t * 4;
  float vals[4];
  {
    const float4 xv = *(const float4*)(xbuf + (size_t)row*SE + i0);
    vals[0] = xv.x; vals[1] = xv.y; vals[2] = xv.z; vals[3] = xv.w;
  }
#pragma unroll
  for (int p = 0; p < KSPLIT; ++p) {
    const bf16x4 pv = *(const bf16x4*)((const short*)parts +
        (size_t)p*ROWS*SE + (size_t)row*SE + i0);
#pragma unroll
    for (int j = 0; j < 4; ++j) vals[j] += bf2f(pv[j]);
  }
  float s1 = vals[0]+vals[1]+vals[2]+vals[3];
  float s2 = vals[0]*vals[0]+vals[1]*vals[1]+vals[2]*vals[2]+vals[3]*vals[3];
  __shared__ float r1[4], r2[4];
  __shared__ float xs[SE];
  __shared__ float red[4][64];
  for (int off = 32; off; off >>= 1) { s1 += __shfl_down(s1, off); s2 += __shfl_down(s2, off); }
  if (lane == 0) { r1[wv_] = s1; r2[wv_] = s2; }
  __syncthreads();
  s1 = r1[0]+r1[1]+r1[2]+r1[3];
  s2 = r2[0]+r2[1]+r2[2]+r2[3];
  const float mu = s1 * (1.f/SE);
  const float var = s2 * (1.f/SE) - mu*mu;
  const float rs = rsqrtf(var + 1e-5f);
  {
    const float4 w4 = *(const float4*)(w + i0);
    const float wv4[4] = {w4.x, w4.y, w4.z, w4.w};
#pragma unroll
    for (int j = 0; j < 4; ++j) xs[i0 + j] = (vals[j]-mu)*rs*wv4[j];
  }
  __syncthreads();
  const int o = och*64 + lane;
  float acc = 0.f;
  const int kbeg = wv_*256;
#pragma unroll 8
  for (int k = kbeg; k < kbeg + 256; ++k)
    acc += xs[k] * pw[(size_t)k*OUTD + o];
  red[wv_][lane] = acc;
  __syncthreads();
  if (t < 64)
    out[(size_t)b*OUTD + och*64 + t] =
        red[0][t] + red[1][t] + red[2][t] + red[3][t] + pb[och*64 + t];
}

// ---------------------------------------------------------------------------
extern "C" void kernel_launch(void* const* d_in, const int* in_sizes, int n_in,
                              void* d_out, int out_size, void* d_ws, size_t ws_size,
                              hipStream_t stream) {
  const float* x_in   = (const float*)d_in[0];
  const float* ln_w   = (const float*)d_in[1];
  const float* w_up   = (const float*)d_in[2];
  const float* conv_w = (const float*)d_in[3];
  const float* conv_b = (const float*)d_in[4];
  const float* wq     = (const float*)d_in[5];
  const float* wk     = (const float*)d_in[6];
  const float* wv     = (const float*)d_in[7];
  const float* ig_w   = (const float*)d_in[8];
  const float* ig_b   = (const float*)d_in[9];
  const float* fg_w   = (const float*)d_in[10];
  const float* fg_b   = (const float*)d_in[11];
  const float* skip   = (const float*)d_in[12];
  const float* mhn_w  = (const float*)d_in[13];
  const float* w_down = (const float*)d_in[14];
  const float* post_w = (const float*)d_in[15];
  const float* proj_w = (const float*)d_in[16];
  const float* proj_b = (const float*)d_in[17];
  float* out = (float*)d_out;

  float* ws = (float*)d_ws;
  float* xbuf   = ws;                                   // ROWS*SE fp32
  float* part   = xbuf  + (size_t)ROWS*SE;              // ROWS*16 fp32
  float* gfold  = part  + (size_t)ROWS*16;              // 8 * 4*8192 fp32
  __hip_bfloat16* cpart = (__hip_bfloat16*)(gfold + (size_t)8*4*8192); // KSPLIT*ROWS*SE bf16
  __hip_bfloat16* lnb   = cpart + (size_t)KSPLIT*ROWS*SE;
  __hip_bfloat16* upbuf = lnb   + (size_t)ROWS*SE;      // ROWS*2*SI bf16
  __hip_bfloat16* xact  = upbuf + (size_t)ROWS*2*SI;    // ROWS*SI bf16
  __hip_bfloat16* qb    = xact  + (size_t)ROWS*SI;      // ROWS*SI [b][h][s][d]
  __hip_bfloat16* kb    = qb    + (size_t)ROWS*SI;
  __hip_bfloat16* vb    = kb    + (size_t)ROWS*SI;
  __hip_bfloat16* habf  = vb    + (size_t)ROWS*SI;      // ROWS*SI
  __hip_bfloat16* wTup  = habf  + (size_t)ROWS*SI;      // 8 * 4096*1024
  __hip_bfloat16* wTdn  = wTup  + (size_t)8*SE*2*SI;    // 8 * 1024*2048

  hipMemcpyAsync(xbuf, x_in, (size_t)ROWS*SE*sizeof(float),
                 hipMemcpyDeviceToDevice, stream);

  // hoisted weight transposes + gate-weight folding (all 8 layers)
  transpose_bf16_kernel<<<dim3(128, 32, 8), 256, 0, stream>>>(w_up, wTup, SE, 2*SI);
  transpose_bf16_kernel<<<dim3(32, 64, 8), 256, 0, stream>>>(w_down, wTdn, SI, SE);
  fold_gate_kernel<<<dim3(8, 8), 256, 0, stream>>>(wq, wk, wv, ig_w, fg_w, gfold);

  for (int blk = 0; blk < 8; ++blk) {
    const float* lw   = ln_w   + (size_t)blk*SE;
    const float* cw   = conv_w + (size_t)blk*SI*4;
    const float* cb   = conv_b + (size_t)blk*SI;
    const float* wqb  = wq     + (size_t)blk*NHQ_*16;
    const float* wkb  = wk     + (size_t)blk*NHQ_*16;
    const float* wvb  = wv     + (size_t)blk*NHQ_*16;
    const float* igbb = ig_b   + (size_t)blk*NHH;
    const float* fgbb = fg_b   + (size_t)blk*NHH;
    const float* skb  = skip   + (size_t)blk*SI;
    const float* mhb  = mhn_w  + (size_t)blk*SI;

    lnres_bf16_kernel<<<ROWS, 256, 0, stream>>>(
        xbuf, cpart, blk == 0 ? 0 : KSPLIT, lw, lnb);
    // up: [2944,1024] x [1024,4096] -> bf16  (736 blocks, %8==0 for swizzle)
    gemm_mfma<<<dim3(32, 23, 1), 256, 0, stream>>>(
        lnb, SE, wTup + (size_t)blk*SE*2*SI, SE, upbuf, 2*SI, SE, 0);
    conv_head_gate_kernel<<<(ROWS/8)*2, 256, 0, stream>>>(
        upbuf, cw, cb, wqb, wkb, wvb, gfold + (size_t)blk*4*8192,
        xact, qb, kb, vb, part);
    mlstm_mfma_kernel<<<SB*NHH, 512, 0, stream>>>(
        qb, kb, vb, part, igbb, fgbb, xact, upbuf, skb, mhb, habf);
    // down: [2944,2048] x [2048,1024] split-K=4 bf16 partials (184/slice, %8==0)
    gemm_mfma<<<dim3(8, 23, KSPLIT), 256, 0, stream>>>(
        habf, SI, wTdn + (size_t)blk*SI*SE, SI, cpart, SE, SI, (size_t)ROWS*SE);
  }
  proj_fused_kernel<<<SB*8, 256, 0, stream>>>(xbuf, cpart, post_w, proj_w, proj_b, out);
}

// Round 19
// 1091.879 us; speedup vs baseline: 1.1998x; 1.0114x over previous
//
#include <hip/hip_runtime.h>
#include <hip/hip_bf16.h>
#include <math.h>

// xLSTM block stack: 8 sequential blocks, then post-LN + projection.
// Round 18: mlstm PV dual accumulators + parallel denominator (8 thr/row);
//           chg 4-step 16-lane reduce. Rest = R17.
//
#define SB   64            // batch
#define SS   46            // seq
#define SE   1024          // embed
#define SI   2048          // inner
#define ROWS (SB*SS)       // 2944
#define NHH  4             // mLSTM heads
#define DHH  512           // head dim
#define NHQ_ 512           // headwise 4x4 heads
#define OUTD 512
#define KSPLIT 4

typedef __attribute__((ext_vector_type(8))) short bf16x8;
typedef __attribute__((ext_vector_type(4))) short bf16x4;
typedef __attribute__((ext_vector_type(4))) float f32x4;

__device__ __forceinline__ void gload_lds16(const void* g, void* lds) {
  __builtin_amdgcn_global_load_lds(
      (const __attribute__((address_space(1))) unsigned int*)g,
      (__attribute__((address_space(3))) unsigned int*)lds, 16, 0, 0);
}

__device__ __forceinline__ float bf2f(short s) {
  union { unsigned int u; float f; } x;
  x.u = ((unsigned int)(unsigned short)s) << 16;
  return x.f;
}

__device__ __forceinline__ short f2bf_rne(float f) {
  union { float f; unsigned int u; } cv; cv.f = f;
  unsigned int lsb = (cv.u >> 16) & 1;
  cv.u += 0x7fff + lsb;
  return (short)(cv.u >> 16);
}

__device__ __forceinline__ float fexp(float x) { return __expf(x); }

// ---------------------------------------------------------------------------
// Fold gate weights through headwise 4x4 maps (all 8 layers).
// gfold layout per layer: [GA|GV|FA|FV][2048][4] fp32 (4*8192 floats).
__global__ __launch_bounds__(256) void fold_gate_kernel(
    const float* __restrict__ wq, const float* __restrict__ wk,
    const float* __restrict__ wv, const float* __restrict__ igw,
    const float* __restrict__ fgw, float* __restrict__ gfold) {
  const int z = blockIdx.y;
  const int c = blockIdx.x * 256 + threadIdx.x;   // 0..2047
  const int hq = c >> 2, d = c & 3;
  const float* wqz = wq + (size_t)z*NHQ_*16;
  const float* wkz = wk + (size_t)z*NHQ_*16;
  const float* wvz = wv + (size_t)z*NHQ_*16;
  const float* igz = igw + (size_t)z*3*SI*NHH;
  const float* fgz = fgw + (size_t)z*3*SI*NHH;
  float ga[4] = {0,0,0,0}, gv[4] = {0,0,0,0};
  float fa[4] = {0,0,0,0}, fv[4] = {0,0,0,0};
#pragma unroll
  for (int o = 0; o < 4; ++o) {
    const float q = wqz[(size_t)hq*16 + o*4 + d];
    const float k = wkz[(size_t)hq*16 + o*4 + d];
    const float v = wvz[(size_t)hq*16 + o*4 + d];
    const float4 iq = *(const float4*)(igz + (size_t)(hq*4 + o)*4);
    const float4 ik = *(const float4*)(igz + (size_t)(2048 + hq*4 + o)*4);
    const float4 iv = *(const float4*)(igz + (size_t)(4096 + hq*4 + o)*4);
    const float4 fq = *(const float4*)(fgz + (size_t)(hq*4 + o)*4);
    const float4 fk = *(const float4*)(fgz + (size_t)(2048 + hq*4 + o)*4);
    const float4 fv4 = *(const float4*)(fgz + (size_t)(4096 + hq*4 + o)*4);
    ga[0] += q*iq.x + k*ik.x; ga[1] += q*iq.y + k*ik.y;
    ga[2] += q*iq.z + k*ik.z; ga[3] += q*iq.w + k*ik.w;
    gv[0] += v*iv.x; gv[1] += v*iv.y; gv[2] += v*iv.z; gv[3] += v*iv.w;
    fa[0] += q*fq.x + k*fk.x; fa[1] += q*fq.y + k*fk.y;
    fa[2] += q*fq.z + k*fk.z; fa[3] += q*fq.w + k*fk.w;
    fv[0] += v*fv4.x; fv[1] += v*fv4.y; fv[2] += v*fv4.z; fv[3] += v*fv4.w;
  }
  float* gz = gfold + (size_t)z*4*8192;
  *(float4*)(gz + 0*8192 + c*4) = (float4){ga[0],ga[1],ga[2],ga[3]};
  *(float4*)(gz + 1*8192 + c*4) = (float4){gv[0],gv[1],gv[2],gv[3]};
  *(float4*)(gz + 2*8192 + c*4) = (float4){fa[0],fa[1],fa[2],fa[3]};
  *(float4*)(gz + 3*8192 + c*4) = (float4){fv[0],fv[1],fv[2],fv[3]};
}

// ---------------------------------------------------------------------------
// Residual-add (npart bf16 split-K partials) + LayerNorm -> bf16; xbuf updated.
__global__ __launch_bounds__(256) void lnres_bf16_kernel(
    float* __restrict__ xbuf, const __hip_bfloat16* __restrict__ parts, int npart,
    const float* __restrict__ w, __hip_bfloat16* __restrict__ out) {
  const int row = blockIdx.x;
  const int t = threadIdx.x;
  const int i0 = t * 4;
  float vals[4];
  {
    const float4 xv = *(const float4*)(xbuf + (size_t)row*SE + i0);
    vals[0] = xv.x; vals[1] = xv.y; vals[2] = xv.z; vals[3] = xv.w;
  }
  for (int p = 0; p < npart; ++p) {
    const bf16x4 pv = *(const bf16x4*)((const short*)parts +
        (size_t)p*ROWS*SE + (size_t)row*SE + i0);
#pragma unroll
    for (int j = 0; j < 4; ++j) vals[j] += bf2f(pv[j]);
  }
  float s1 = vals[0]+vals[1]+vals[2]+vals[3];
  float s2 = vals[0]*vals[0]+vals[1]*vals[1]+vals[2]*vals[2]+vals[3]*vals[3];
  if (npart) {
    float4 st = {vals[0], vals[1], vals[2], vals[3]};
    *(float4*)(xbuf + (size_t)row*SE + i0) = st;
  }
  __shared__ float r1[4], r2[4];
  for (int off = 32; off; off >>= 1) { s1 += __shfl_down(s1, off); s2 += __shfl_down(s2, off); }
  if ((t & 63) == 0) { r1[t >> 6] = s1; r2[t >> 6] = s2; }
  __syncthreads();
  s1 = r1[0]+r1[1]+r1[2]+r1[3];
  s2 = r2[0]+r2[1]+r2[2]+r2[3];
  const float mu = s1 * (1.f/SE);
  const float var = s2 * (1.f/SE) - mu*mu;
  const float rs = rsqrtf(var + 1e-5f);
  const float4 w4 = *(const float4*)(w + i0);
  const float wv[4] = {w4.x, w4.y, w4.z, w4.w};
  bf16x4 o;
#pragma unroll
  for (int j = 0; j < 4; ++j) o[j] = f2bf_rne((vals[j]-mu)*rs*wv[j]);
  *(bf16x4*)((short*)out + (size_t)row*SE + i0) = o;
}

// ---------------------------------------------------------------------------
// Transpose + convert (all 8 layers): W [z][K][N] fp32 -> Wt [z][N][K] bf16.
__global__ __launch_bounds__(256) void transpose_bf16_kernel(
    const float* __restrict__ W, __hip_bfloat16* __restrict__ Wt, int K, int N) {
  __shared__ float tile[32][33];
  const int z = blockIdx.z;
  const float* Wz = W + (size_t)z*K*N;
  __hip_bfloat16* Wtz = Wt + (size_t)z*K*N;
  const int k0 = blockIdx.y * 32, n0 = blockIdx.x * 32;
  const int tr = threadIdx.x >> 5;
  const int tc = threadIdx.x & 31;
#pragma unroll
  for (int i = 0; i < 4; ++i)
    tile[tr + i*8][tc] = Wz[(size_t)(k0 + tr + i*8)*N + n0 + tc];
  __syncthreads();
#pragma unroll
  for (int i = 0; i < 4; ++i)
    Wtz[(size_t)(n0 + tr + i*8)*K + k0 + tc] = __float2bfloat16(tile[tc][tr + i*8]);
}

// ---------------------------------------------------------------------------
// bf16 MFMA GEMM: C[M,N] = A[M,K_z] * Bt[N,K_z]^T over this z's K-slice.
// 128x128 tile, BK=32, 2-phase pipelined K-loop (counted vmcnt, raw barriers).
// XCD-aware bijective block swizzle (requires gx*gy % 8 == 0).
__global__ __launch_bounds__(256) void gemm_mfma(
    const __hip_bfloat16* __restrict__ A, int lda,
    const __hip_bfloat16* __restrict__ Bt, int ldb,
    __hip_bfloat16* __restrict__ Cv, int ldc, int K, size_t cstride) {
  __shared__ short As[2][128*32];
  __shared__ short Bs[2][128*32];
  const int t = threadIdx.x;
  const int lane = t & 63;
  const int w = t >> 6;
  const int wr = w >> 1, wc = w & 1;
  const int l15 = lane & 15, lg = lane >> 4;

  const int nxy = gridDim.x * gridDim.y;
  int flat = blockIdx.y * gridDim.x + blockIdx.x;
  const int cpx = nxy >> 3;
  flat = (flat & 7) * cpx + (flat >> 3);
  const int bx = flat % gridDim.x;
  const int by = flat / gridDim.x;

  const int row0 = by * 128, col0 = bx * 128;
  const int Kper = K / gridDim.z;
  const int kbeg = blockIdx.z * Kper, kend = kbeg + Kper;
  f32x4 acc[4][4];
#pragma unroll
  for (int m = 0; m < 4; ++m)
#pragma unroll
    for (int n = 0; n < 4; ++n) acc[m][n] = (f32x4){0.f,0.f,0.f,0.f};

  const int L0 = t*16;
  const int L1 = 4096 + t*16;
  const int r0s = L0 >> 6, k0s = (L0 & 63) >> 1;
  const int r1s = L1 >> 6, k1s = (L1 & 63) >> 1;

#define STAGE(buf, kk0)                                                        \
  do {                                                                         \
    gload_lds16(A  + (size_t)(row0 + r0s)*lda + (kk0) + k0s, (char*)As[buf] + L0); \
    gload_lds16(A  + (size_t)(row0 + r1s)*lda + (kk0) + k1s, (char*)As[buf] + L1); \
    gload_lds16(Bt + (size_t)(col0 + r0s)*ldb + (kk0) + k0s, (char*)Bs[buf] + L0); \
    gload_lds16(Bt + (size_t)(col0 + r1s)*ldb + (kk0) + k1s, (char*)Bs[buf] + L1); \
  } while (0)

  int cur = 0;
  STAGE(0, kbeg);
  for (int k0 = kbeg; k0 < kend; k0 += 32) {
    const bool haveNext = (k0 + 32 < kend);
    if (haveNext) {
      STAGE(cur ^ 1, k0 + 32);
      asm volatile("s_waitcnt vmcnt(4)" ::: "memory");
    } else {
      asm volatile("s_waitcnt vmcnt(0)" ::: "memory");
    }
    __builtin_amdgcn_sched_barrier(0);
    __builtin_amdgcn_s_barrier();
    bf16x8 af[4], bfr[4];
#pragma unroll
    for (int m = 0; m < 4; ++m)
      af[m] = *(const bf16x8*)&As[cur][(wr*64 + m*16 + l15)*32 + lg*8];
#pragma unroll
    for (int n = 0; n < 4; ++n)
      bfr[n] = *(const bf16x8*)&Bs[cur][(wc*64 + n*16 + l15)*32 + lg*8];
#pragma unroll
    for (int m = 0; m < 4; ++m)
#pragma unroll
      for (int n = 0; n < 4; ++n)
        acc[m][n] = __builtin_amdgcn_mfma_f32_16x16x32_bf16(af[m], bfr[n], acc[m][n], 0, 0, 0);
    asm volatile("s_waitcnt lgkmcnt(0)" ::: "memory");
    __builtin_amdgcn_sched_barrier(0);
    __builtin_amdgcn_s_barrier();
    cur ^= 1;
  }
#undef STAGE

  __hip_bfloat16* Cz = Cv + blockIdx.z * cstride;
#pragma unroll
  for (int m = 0; m < 4; ++m) {
#pragma unroll
    for (int n = 0; n < 4; ++n) {
      const int cc = col0 + wc*64 + n*16 + l15;
#pragma unroll
      for (int j = 0; j < 4; ++j) {
        const int rr = row0 + wr*64 + m*16 + lg*4 + j;
        Cz[(size_t)rr*ldc + cc] = __float2bfloat16(acc[m][n][j]);
      }
    }
  }
}

// ---------------------------------------------------------------------------
// Fused v8 (8 rows x 1024 channels per block; thread owns 4-channel group):
// causal conv(K=4)+SiLU -> xact bf16; headwise 4x4 q/k/v (thread-local) -> bf16;
// gate partials from folded weights -> part[row][chunk*8+g]. 4-step reduce.
__global__ __launch_bounds__(256) void conv_head_gate_kernel(
    const __hip_bfloat16* __restrict__ up, const float* __restrict__ cw,
    const float* __restrict__ cb,
    const float* __restrict__ wq, const float* __restrict__ wk,
    const float* __restrict__ wv,
    const float* __restrict__ gfold,
    __hip_bfloat16* __restrict__ xact,
    __hip_bfloat16* __restrict__ qb, __hip_bfloat16* __restrict__ kb,
    __hip_bfloat16* __restrict__ vb, float* __restrict__ part) {
  const int rblk  = blockIdx.x >> 1;       // 0..367 (8 rows each)
  const int chunk = blockIdx.x & 1;        // 0..1 (1024 channels each)
  const int r0 = rblk * 8;
  const int t = threadIdx.x;
  const int c4 = chunk*1024 + t*4;         // first of this thread's 4 channels
  const int lane = t & 63, wv_ = t >> 6;

  float wtap[4][4], bias[4];
#pragma unroll
  for (int j = 0; j < 4; ++j) {
    const float4 w4 = *(const float4*)(cw + (size_t)(c4 + j)*4);
    wtap[j][0] = w4.x; wtap[j][1] = w4.y; wtap[j][2] = w4.z; wtap[j][3] = w4.w;
  }
  {
    const float4 b4 = *(const float4*)(cb + c4);
    bias[0] = b4.x; bias[1] = b4.y; bias[2] = b4.z; bias[3] = b4.w;
  }
  const size_t hqo = (size_t)(c4 >> 2) * 16;
  float wqm[4][4], wkm[4][4], wvm[4][4];
#pragma unroll
  for (int o = 0; o < 4; ++o) {
    const float4 a = *(const float4*)(wq + hqo + o*4);
    const float4 b = *(const float4*)(wk + hqo + o*4);
    const float4 c = *(const float4*)(wv + hqo + o*4);
    wqm[o][0]=a.x; wqm[o][1]=a.y; wqm[o][2]=a.z; wqm[o][3]=a.w;
    wkm[o][0]=b.x; wkm[o][1]=b.y; wkm[o][2]=b.z; wkm[o][3]=b.w;
    wvm[o][0]=c.x; wvm[o][1]=c.y; wvm[o][2]=c.z; wvm[o][3]=c.w;
  }
  // folded gate weights: 16 float4 in registers
  float4 gav[4], gvv[4], fav[4], fvv[4];
#pragma unroll
  for (int j = 0; j < 4; ++j) {
    gav[j] = *(const float4*)(gfold + 0*8192 + (size_t)(c4+j)*4);
    gvv[j] = *(const float4*)(gfold + 1*8192 + (size_t)(c4+j)*4);
    fav[j] = *(const float4*)(gfold + 2*8192 + (size_t)(c4+j)*4);
    fvv[j] = *(const float4*)(gfold + 3*8192 + (size_t)(c4+j)*4);
  }

  // input rows r0-3 .. r0+7 (11 rows) as short4
  bf16x4 u[11];
#pragma unroll
  for (int i = 0; i < 11; ++i) {
    const int gr = r0 - 3 + i;
    u[i] = (gr >= 0) ? *(const bf16x4*)((const short*)up + (size_t)gr*(2*SI) + c4)
                     : (bf16x4){0,0,0,0};
  }

  __shared__ float red[8][16][8];   // [row][16-lane group][gate]

  const int h = c4 >> 9, dd = c4 & 511;
#pragma unroll
  for (int rr = 0; rr < 8; ++rr) {
    const int row = r0 + rr;
    const int b = row / SS, s = row - (row / SS)*SS;
    float xa[4], xin[4];
#pragma unroll
    for (int j = 0; j < 4; ++j) {
      float acc = bias[j];
#pragma unroll
      for (int tap = 0; tap < 4; ++tap)
        if (s - 3 + tap >= 0) acc += bf2f(u[rr + tap][j]) * wtap[j][tap];
      xa[j] = acc / (1.f + fexp(-acc));
      xin[j] = bf2f(u[rr + 3][j]);
    }
    {
      bf16x4 xo;
#pragma unroll
      for (int j = 0; j < 4; ++j) xo[j] = f2bf_rne(xa[j]);
      *(bf16x4*)((short*)xact + (size_t)row*SI + c4) = xo;
    }
    float q[4], k[4], v[4];
#pragma unroll
    for (int o = 0; o < 4; ++o) {
      float aq = 0.f, ak = 0.f, av = 0.f;
#pragma unroll
      for (int d = 0; d < 4; ++d) {
        aq += xa[d] * wqm[o][d];
        ak += xa[d] * wkm[o][d];
        av += xin[d] * wvm[o][d];
      }
      q[o] = aq; k[o] = ak; v[o] = av;
    }
    const size_t dst = (((size_t)b*NHH + h)*SS + s)*DHH + dd;
    {
      bf16x4 qo, ko, vo;
#pragma unroll
      for (int j = 0; j < 4; ++j) {
        qo[j] = f2bf_rne(q[j]); ko[j] = f2bf_rne(k[j]); vo[j] = f2bf_rne(v[j]);
      }
      *(bf16x4*)((short*)qb + dst) = qo;
      *(bf16x4*)((short*)kb + dst) = ko;
      *(bf16x4*)((short*)vb + dst) = vo;
    }
    // gate partials from folded weights (xa, xin directly)
    float a8[8] = {0,0,0,0,0,0,0,0};
#pragma unroll
    for (int j = 0; j < 4; ++j) {
      a8[0] += xa[j]*gav[j].x + xin[j]*gvv[j].x;
      a8[1] += xa[j]*gav[j].y + xin[j]*gvv[j].y;
      a8[2] += xa[j]*gav[j].z + xin[j]*gvv[j].z;
      a8[3] += xa[j]*gav[j].w + xin[j]*gvv[j].w;
      a8[4] += xa[j]*fav[j].x + xin[j]*fvv[j].x;
      a8[5] += xa[j]*fav[j].y + xin[j]*fvv[j].y;
      a8[6] += xa[j]*fav[j].z + xin[j]*fvv[j].z;
      a8[7] += xa[j]*fav[j].w + xin[j]*fvv[j].w;
    }
    // 4-step reduce within 16-lane groups
    for (int off = 8; off; off >>= 1)
#pragma unroll
      for (int g = 0; g < 8; ++g) a8[g] += __shfl_down(a8[g], off);
    if ((lane & 15) == 0)
#pragma unroll
      for (int g = 0; g < 8; ++g) red[rr][wv_*4 + (lane >> 4)][g] = a8[g];
  }
  __syncthreads();
  if (t < 64) {
    const int rr = t >> 3, g = t & 7;
    float sres = 0.f;
#pragma unroll
    for (int p = 0; p < 16; ++p) sres += red[rr][p][g];
    part[(size_t)(r0 + rr)*16 + chunk*8 + g] = sres;
  }
}

// ---------------------------------------------------------------------------
// mLSTM per (b,head), 8 waves (512 thr): gate reduce + MFMA QK^T + parallel
// log-sigmoid scan (Kogge-Stone in wave 0) + dual-acc VALU PV + fused
// multi-head norm/skip/gate epilogue -> habf bf16 [b*s][2048].
__global__ __launch_bounds__(512) void mlstm_mfma_kernel(
    const __hip_bfloat16* __restrict__ qb, const __hip_bfloat16* __restrict__ kb,
    const __hip_bfloat16* __restrict__ vb,
    const float* __restrict__ part,
    const float* __restrict__ igb, const float* __restrict__ fgb,
    const __hip_bfloat16* __restrict__ xact, const __hip_bfloat16* __restrict__ up,
    const float* __restrict__ skip, const float* __restrict__ mhn,
    __hip_bfloat16* __restrict__ habf) {
  const int bh = blockIdx.x;                 // b*4 + h
  const int b = bh >> 2, h = bh & 3;
  const int t = threadIdx.x;
  const int lane = t & 63, wid = t >> 6;     // wid 0..7
  const int l15 = lane & 15, lg = lane >> 4;

  __shared__ short QKs[2][48*264];
  __shared__ float Cs[46][48];
  __shared__ float cum[46], mmv[46], ips[46], fps[46], inv[46];
  short* Vs = &QKs[0][0];                    // alias: V [46][520] bf16

  if (t < SS) {
    const float* pr = part + (size_t)(b*SS + t)*16;
    float si = igb[h], sf = fgb[h];
#pragma unroll
    for (int ch = 0; ch < 2; ++ch) { si += pr[ch*8 + h]; sf += pr[ch*8 + 4 + h]; }
    ips[t] = si; fps[t] = sf;
  }

  int prs[2]; int np = 0;
  for (int p = wid; p < 9; p += 8) prs[np++] = p;
  f32x4 acc[2];
#pragma unroll
  for (int i = 0; i < 2; ++i) acc[i] = (f32x4){0.f,0.f,0.f,0.f};

  for (int ph = 0; ph < 2; ++ph) {
    __syncthreads();
    for (int i = t; i < 48*32; i += 512) {
      const int row = i >> 5, oc = i & 31;
      bf16x8 vq = {0,0,0,0,0,0,0,0}, vk = {0,0,0,0,0,0,0,0};
      if (row < SS) {
        const size_t src = ((size_t)bh*SS + row)*DHH + ph*256 + oc*8;
        vq = *(const bf16x8*)(qb + src);
        vk = *(const bf16x8*)(kb + src);
      }
      *(bf16x8*)&QKs[0][row*264 + oc*8] = vq;
      *(bf16x8*)&QKs[1][row*264 + oc*8] = vk;
    }
    __syncthreads();
#pragma unroll
    for (int kc = 0; kc < 8; ++kc) {
      for (int i = 0; i < np; ++i) {
        const int mt = prs[i] / 3, nt = prs[i] - 3*(prs[i]/3);
        const bf16x8 a = *(const bf16x8*)&QKs[0][(mt*16 + l15)*264 + kc*32 + lg*8];
        const bf16x8 bb = *(const bf16x8*)&QKs[1][(nt*16 + l15)*264 + kc*32 + lg*8];
        acc[i] = __builtin_amdgcn_mfma_f32_16x16x32_bf16(a, bb, acc[i], 0, 0, 0);
      }
    }
  }
  __syncthreads();
  // parallel log-sigmoid cumsum + running-max scan (wave 0, Kogge-Stone)
  if (wid == 0) {
    const int s = lane;
    float lf = 0.f;
    if (s < SS) {
      const float xv = fps[s];
      lf = fminf(xv, 0.f) - log1pf(expf(-fabsf(xv)));
    }
#pragma unroll
    for (int off = 1; off < 64; off <<= 1) {
      const float o = __shfl_up(lf, off);
      if (lane >= off) lf += o;
    }
    float e = (s < SS) ? (ips[s] - lf) : -INFINITY;
#pragma unroll
    for (int off = 1; off < 64; off <<= 1) {
      const float o = __shfl_up(e, off);
      if (lane >= off) e = fmaxf(e, o);
    }
    if (s < SS) { cum[s] = lf; mmv[s] = lf + e; }
  }
  for (int i = t; i < SS*64; i += 512) {
    const int row = i >> 6, oc = i & 63;
    *(bf16x8*)&Vs[row*520 + oc*8] =
        *(const bf16x8*)(vb + ((size_t)bh*SS + row)*DHH + oc*8);
  }
  __syncthreads();
  const float rsq = 0.04419417382415922f;
  for (int i = 0; i < np; ++i) {
    const int mt = prs[i] / 3, nt = prs[i] - 3*(prs[i]/3);
    const int s = nt*16 + l15;
    if (s < SS) {
#pragma unroll
      for (int j = 0; j < 4; ++j) {
        const int tt = mt*16 + lg*4 + j;
        if (tt < SS) {
          float wgt = 0.f;
          if (s <= tt) wgt = rsq * fexp(cum[tt] - cum[s] + ips[s] - mmv[tt]);
          Cs[tt][s] = acc[i][j] * wgt;
        }
      }
    }
  }
  __syncthreads();
  // parallel denominator: 8 threads per t-row, 3-step shfl reduce
  if (t < SS*8) {
    const int tt = t >> 3, g = t & 7;
    float ssum = 0.f;
    for (int s = g; s <= tt; s += 8) ssum += Cs[tt][s];
    ssum += __shfl_xor(ssum, 1);
    ssum += __shfl_xor(ssum, 2);
    ssum += __shfl_xor(ssum, 4);
    if (g == 0)
      inv[tt] = 1.f / (fmaxf(fabsf(ssum), fexp(-mmv[tt])) + 1e-6f);
  }
  __syncthreads();
  const int c0 = h*DHH + lane*8;
  for (int it = 0; it < 6; ++it) {
    const int tt = wid + it*8;
    if (tt >= SS) break;
    float a[8], b2[8];
#pragma unroll
    for (int j = 0; j < 8; ++j) { a[j] = 0.f; b2[j] = 0.f; }
    int s = 0;
    for (; s + 1 <= tt; s += 2) {
      const float ca = Cs[tt][s];
      const float cb2 = Cs[tt][s+1];
      const bf16x8 v80 = *(const bf16x8*)&Vs[s*520 + lane*8];
      const bf16x8 v81 = *(const bf16x8*)&Vs[(s+1)*520 + lane*8];
#pragma unroll
      for (int j = 0; j < 8; ++j) {
        a[j]  += ca  * bf2f(v80[j]);
        b2[j] += cb2 * bf2f(v81[j]);
      }
    }
    if (s <= tt) {
      const float ca = Cs[tt][s];
      const bf16x8 v80 = *(const bf16x8*)&Vs[s*520 + lane*8];
#pragma unroll
      for (int j = 0; j < 8; ++j) a[j] += ca * bf2f(v80[j]);
    }
#pragma unroll
    for (int j = 0; j < 8; ++j) a[j] += b2[j];
    const float sc = inv[tt];
    float s1 = 0.f, s2 = 0.f;
#pragma unroll
    for (int j = 0; j < 8; ++j) { a[j] *= sc; s1 += a[j]; s2 += a[j]*a[j]; }
#pragma unroll
    for (int off = 1; off < 64; off <<= 1) {
      s1 += __shfl_xor(s1, off); s2 += __shfl_xor(s2, off);
    }
    const float mu = s1 * (1.f/512.f);
    const float var = s2 * (1.f/512.f) - mu*mu;
    const float rs = rsqrtf(var + 1e-5f);
    const int row = b*SS + tt;
    const bf16x8 xa8 = *(const bf16x8*)((const short*)xact + (size_t)row*SI + c0);
    const bf16x8 z8 = *(const bf16x8*)((const short*)up + (size_t)row*(2*SI) + SI + c0);
    const float4 mh0 = *(const float4*)(mhn + c0);
    const float4 mh1 = *(const float4*)(mhn + c0 + 4);
    const float4 sk0 = *(const float4*)(skip + c0);
    const float4 sk1 = *(const float4*)(skip + c0 + 4);
    const float mhv[8] = {mh0.x,mh0.y,mh0.z,mh0.w,mh1.x,mh1.y,mh1.z,mh1.w};
    const float skv[8] = {sk0.x,sk0.y,sk0.z,sk0.w,sk1.x,sk1.y,sk1.z,sk1.w};
    bf16x8 o8;
#pragma unroll
    for (int j = 0; j < 8; ++j) {
      const float hv = (a[j]-mu)*rs*mhv[j] + skv[j]*bf2f(xa8[j]);
      const float zv = bf2f(z8[j]);
      o8[j] = f2bf_rne(hv * (zv / (1.f + fexp(-zv))));
    }
    *(bf16x8*)((short*)habf + (size_t)row*SI + c0) = o8;
  }
}

// ---------------------------------------------------------------------------
// Fused post-LN (residual + bf16 split-K partials) + projection.
__global__ __launch_bounds__(256) void proj_fused_kernel(
    const float* __restrict__ xbuf, const __hip_bfloat16* __restrict__ parts,
    const float* __restrict__ w, const float* __restrict__ pw,
    const float* __restrict__ pb, float* __restrict__ out) {
  const int b = blockIdx.x >> 3;
  const int och = blockIdx.x & 7;
  const int row = b*SS + SS - 1;
  const int t = threadIdx.x;
  const int wv_ = t >> 6, lane = t & 63;
  const int i0 = t * 4;
  float vals[4];
  {
    const float4 xv = *(const float4*)(xbuf + (size_t)row*SE + i0);
    vals[0] = xv.x; vals[1] = xv.y; vals[2] = xv.z; vals[3] = xv.w;
  }
#pragma unroll
  for (int p = 0; p < KSPLIT; ++p) {
    const bf16x4 pv = *(const bf16x4*)((const short*)parts +
        (size_t)p*ROWS*SE + (size_t)row*SE + i0);
#pragma unroll
    for (int j = 0; j < 4; ++j) vals[j] += bf2f(pv[j]);
  }
  float s1 = vals[0]+vals[1]+vals[2]+vals[3];
  float s2 = vals[0]*vals[0]+vals[1]*vals[1]+vals[2]*vals[2]+vals[3]*vals[3];
  __shared__ float r1[4], r2[4];
  __shared__ float xs[SE];
  __shared__ float red[4][64];
  for (int off = 32; off; off >>= 1) { s1 += __shfl_down(s1, off); s2 += __shfl_down(s2, off); }
  if (lane == 0) { r1[wv_] = s1; r2[wv_] = s2; }
  __syncthreads();
  s1 = r1[0]+r1[1]+r1[2]+r1[3];
  s2 = r2[0]+r2[1]+r2[2]+r2[3];
  const float mu = s1 * (1.f/SE);
  const float var = s2 * (1.f/SE) - mu*mu;
  const float rs = rsqrtf(var + 1e-5f);
  {
    const float4 w4 = *(const float4*)(w + i0);
    const float wv4[4] = {w4.x, w4.y, w4.z, w4.w};
#pragma unroll
    for (int j = 0; j < 4; ++j) xs[i0 + j] = (vals[j]-mu)*rs*wv4[j];
  }
  __syncthreads();
  const int o = och*64 + lane;
  float acc = 0.f;
  const int kbeg = wv_*256;
#pragma unroll 8
  for (int k = kbeg; k < kbeg + 256; ++k)
    acc += xs[k] * pw[(size_t)k*OUTD + o];
  red[wv_][lane] = acc;
  __syncthreads();
  if (t < 64)
    out[(size_t)b*OUTD + och*64 + t] =
        red[0][t] + red[1][t] + red[2][t] + red[3][t] + pb[och*64 + t];
}

// ---------------------------------------------------------------------------
extern "C" void kernel_launch(void* const* d_in, const int* in_sizes, int n_in,
                              void* d_out, int out_size, void* d_ws, size_t ws_size,
                              hipStream_t stream) {
  const float* x_in   = (const float*)d_in[0];
  const float* ln_w   = (const float*)d_in[1];
  const float* w_up   = (const float*)d_in[2];
  const float* conv_w = (const float*)d_in[3];
  const float* conv_b = (const float*)d_in[4];
  const float* wq     = (const float*)d_in[5];
  const float* wk     = (const float*)d_in[6];
  const float* wv     = (const float*)d_in[7];
  const float* ig_w   = (const float*)d_in[8];
  const float* ig_b   = (const float*)d_in[9];
  const float* fg_w   = (const float*)d_in[10];
  const float* fg_b   = (const float*)d_in[11];
  const float* skip   = (const float*)d_in[12];
  const float* mhn_w  = (const float*)d_in[13];
  const float* w_down = (const float*)d_in[14];
  const float* post_w = (const float*)d_in[15];
  const float* proj_w = (const float*)d_in[16];
  const float* proj_b = (const float*)d_in[17];
  float* out = (float*)d_out;

  float* ws = (float*)d_ws;
  float* xbuf   = ws;                                   // ROWS*SE fp32
  float* part   = xbuf  + (size_t)ROWS*SE;              // ROWS*16 fp32
  float* gfold  = part  + (size_t)ROWS*16;              // 8 * 4*8192 fp32
  __hip_bfloat16* cpart = (__hip_bfloat16*)(gfold + (size_t)8*4*8192); // KSPLIT*ROWS*SE bf16
  __hip_bfloat16* lnb   = cpart + (size_t)KSPLIT*ROWS*SE;
  __hip_bfloat16* upbuf = lnb   + (size_t)ROWS*SE;      // ROWS*2*SI bf16
  __hip_bfloat16* xact  = upbuf + (size_t)ROWS*2*SI;    // ROWS*SI bf16
  __hip_bfloat16* qb    = xact  + (size_t)ROWS*SI;      // ROWS*SI [b][h][s][d]
  __hip_bfloat16* kb    = qb    + (size_t)ROWS*SI;
  __hip_bfloat16* vb    = kb    + (size_t)ROWS*SI;
  __hip_bfloat16* habf  = vb    + (size_t)ROWS*SI;      // ROWS*SI
  __hip_bfloat16* wTup  = habf  + (size_t)ROWS*SI;      // 8 * 4096*1024
  __hip_bfloat16* wTdn  = wTup  + (size_t)8*SE*2*SI;    // 8 * 1024*2048

  hipMemcpyAsync(xbuf, x_in, (size_t)ROWS*SE*sizeof(float),
                 hipMemcpyDeviceToDevice, stream);

  // hoisted weight transposes + gate-weight folding (all 8 layers)
  transpose_bf16_kernel<<<dim3(128, 32, 8), 256, 0, stream>>>(w_up, wTup, SE, 2*SI);
  transpose_bf16_kernel<<<dim3(32, 64, 8), 256, 0, stream>>>(w_down, wTdn, SI, SE);
  fold_gate_kernel<<<dim3(8, 8), 256, 0, stream>>>(wq, wk, wv, ig_w, fg_w, gfold);

  for (int blk = 0; blk < 8; ++blk) {
    const float* lw   = ln_w   + (size_t)blk*SE;
    const float* cw   = conv_w + (size_t)blk*SI*4;
    const float* cb   = conv_b + (size_t)blk*SI;
    const float* wqb  = wq     + (size_t)blk*NHQ_*16;
    const float* wkb  = wk     + (size_t)blk*NHQ_*16;
    const float* wvb  = wv     + (size_t)blk*NHQ_*16;
    const float* igbb = ig_b   + (size_t)blk*NHH;
    const float* fgbb = fg_b   + (size_t)blk*NHH;
    const float* skb  = skip   + (size_t)blk*SI;
    const float* mhb  = mhn_w  + (size_t)blk*SI;

    lnres_bf16_kernel<<<ROWS, 256, 0, stream>>>(
        xbuf, cpart, blk == 0 ? 0 : KSPLIT, lw, lnb);
    // up: [2944,1024] x [1024,4096] -> bf16  (736 blocks, %8==0 for swizzle)
    gemm_mfma<<<dim3(32, 23, 1), 256, 0, stream>>>(
        lnb, SE, wTup + (size_t)blk*SE*2*SI, SE, upbuf, 2*SI, SE, 0);
    conv_head_gate_kernel<<<(ROWS/8)*2, 256, 0, stream>>>(
        upbuf, cw, cb, wqb, wkb, wvb, gfold + (size_t)blk*4*8192,
        xact, qb, kb, vb, part);
    mlstm_mfma_kernel<<<SB*NHH, 512, 0, stream>>>(
        qb, kb, vb, part, igbb, fgbb, xact, upbuf, skb, mhb, habf);
    // down: [2944,2048] x [2048,1024] split-K=4 bf16 partials (184/slice, %8==0)
    gemm_mfma<<<dim3(8, 23, KSPLIT), 256, 0, stream>>>(
        habf, SI, wTdn + (size_t)blk*SI*SE, SI, cpart, SE, SI, (size_t)ROWS*SE);
  }
  proj_fused_kernel<<<SB*8, 256, 0, stream>>>(xbuf, cpart, post_w, proj_w, proj_b, out);
}